// Round 7
// baseline (222.840 us; speedup 1.0000x reference)
//
#include <hip/hip_runtime.h>
#include <hip/hip_bf16.h>

// InnocentAttention: B=4 H=16 S=2048 D=64, fp32 in/out, per-batch event_length mask.
//
// R12: wave-independent consumers + XCD-affinity queues + 2-deep register
// double-buffer. R11 proved affinity fixes traffic (FETCH 52->18.6MB) but the
// 8-wave barrier lockstep leaves ~5.5k cyc/tile exposed (one item per block ->
// wall = one serial 32-tile chain). R8 proved the wave-independent data path
// works but died on cross-XCD L3 traffic. This kernel: each WAVE pulls a 32-q
// item from its group's queue (group = blockIdx%8 = head%8 -> own-XCD L2 reads),
// reads fragment-ordered K/V lines straight to REGISTERS (16x dwordx4/tile),
// pipelined A/B with static indexing, zero LDS, zero barriers. Prepass
// unchanged. Falls back to the proven R5 path when ws_size < ~33.6 MB.

#define SQ 2048
#define DH 64
#define NBH 64
#define TK 64
#define NTILE 32           // SQ / TK
#define TILE_B 8192        // TK * DH * 2 bytes (bf16)
#define LDE 72             // fallback-path padded LDS stride
#define LVP 68             // prepass V-stage stride

typedef __attribute__((ext_vector_type(4))) float f32x4;
typedef __attribute__((ext_vector_type(8))) short bf16x8;
typedef __attribute__((ext_vector_type(4))) unsigned int u32x4;
typedef __attribute__((ext_vector_type(2))) unsigned int u32x2;

__device__ __forceinline__ unsigned int pk2(float lo, float hi) {
    // v_cvt_pk_bf16_f32 on gfx950 (RNE), lo -> low 16 bits
    __hip_bfloat162 h = __float22bfloat162_rn(float2{lo, hi});
    union { __hip_bfloat162 h; unsigned int u; } c; c.h = h;
    return c.u;
}

__device__ __forceinline__ float bfu16_to_f(unsigned short s) {
    union { unsigned int u; float f; } c; c.u = ((unsigned int)s) << 16;
    return c.f;
}

// ============================================================================
// NEW PATH
// ============================================================================

// Prepass (validated R8-R11): one block per (bh, 64-key tile). Fragment-ordered:
//  K tile: line fi = mt*2+half (1KB); lane l=(qd*16+c): 16B =
//          K[key=mt*16+c][d = half*32+qd*8 .. +7] bf16.
//  V tile: line fi = kc*4+dt; lane l: element j =
//          V[key = kc*32 + (j>>2)*16 + qd*4 + (j&3)][d = dt*16+c]  (pi order)
//  MV[bh][d] += mean contribution of this tile's 64 V rows (atomic)
__global__ __launch_bounds__(256)
void convkv(const float* __restrict__ K, const float* __restrict__ V,
            const int* __restrict__ EL, float* __restrict__ MV,
            char* __restrict__ Kbt, char* __restrict__ Vbt) {
    const int bh = blockIdx.x >> 5;
    const int kt = blockIdx.x & 31;
    const int k0 = kt * TK;
    const int el = EL[bh >> 4];
    const int t = threadIdx.x;
    const int r  = t >> 2;      // key row 0..63
    const int dc = t & 3;       // 16-d chunk

    __shared__ short LV[64][LVP];

    // stage V row (bf16) into LDS for transpose + mean
    {
        const float* vp = V + ((size_t)bh * SQ + k0 + r) * DH + dc * 16;
        f32x4 a = *(const f32x4*)vp;
        f32x4 b = *(const f32x4*)(vp + 4);
        f32x4 c2 = *(const f32x4*)(vp + 8);
        f32x4 d2 = *(const f32x4*)(vp + 12);
        u32x4 w0, w1;
        w0[0] = pk2(a[0], a[1]);  w0[1] = pk2(a[2], a[3]);
        w0[2] = pk2(b[0], b[1]);  w0[3] = pk2(b[2], b[3]);
        w1[0] = pk2(c2[0], c2[1]); w1[1] = pk2(c2[2], c2[3]);
        w1[2] = pk2(d2[0], d2[1]); w1[3] = pk2(d2[2], d2[3]);
        *(u32x4*)&LV[r][dc * 16]     = w0;
        *(u32x4*)&LV[r][dc * 16 + 8] = w1;
    }

    // K convert (valid tiles only) -> fragment-ordered lines
    if (k0 < el) {
        const float* kp = K + ((size_t)bh * SQ + k0 + r) * DH + dc * 16;
        f32x4 a = *(const f32x4*)kp;
        f32x4 b = *(const f32x4*)(kp + 4);
        f32x4 c2 = *(const f32x4*)(kp + 8);
        f32x4 d2 = *(const f32x4*)(kp + 12);
        u32x4 w0, w1;
        w0[0] = pk2(a[0], a[1]);  w0[1] = pk2(a[2], a[3]);
        w0[2] = pk2(b[0], b[1]);  w0[3] = pk2(b[2], b[3]);
        w1[0] = pk2(c2[0], c2[1]); w1[1] = pk2(c2[2], c2[3]);
        w1[2] = pk2(d2[0], d2[1]); w1[3] = pk2(d2[2], d2[3]);
        char* kb = Kbt + (size_t)(bh * NTILE + kt) * TILE_B;
        const int fi  = (r >> 4) * 2 + (dc >> 1);
        const int qd0 = (dc & 1) * 2;
        char* d0 = kb + fi * 1024 + qd0 * 256 + (r & 15) * 16;
        *(u32x4*)d0         = w0;
        *(u32x4*)(d0 + 256) = w1;
    }

    __syncthreads();

    // transpose-read V in pi order + mean partial
    const int dd  = t >> 2;     // d row 0..63
    const int seg = t & 3;      // 16-pos segment
    float msum = 0.f;
    unsigned int wv[8];
    #pragma unroll
    for (int i = 0; i < 8; ++i) {
        const int pos = seg * 16 + 2 * i;
        const int key = (pos & ~31) | ((pos & 4) << 2) | ((pos & 24) >> 1) | (pos & 3);
        const unsigned short s0 = (unsigned short)LV[key][dd];
        const unsigned short s1 = (unsigned short)LV[key + 1][dd];
        msum += bfu16_to_f(s0) + bfu16_to_f(s1);
        wv[i] = (unsigned int)s0 | ((unsigned int)s1 << 16);
    }
    msum += __shfl_xor(msum, 1);
    msum += __shfl_xor(msum, 2);
    if (seg == 0) atomicAdd(&MV[bh * DH + dd], msum * (1.0f / (float)SQ));

    if (k0 < el) {
        char* vbb = Vbt + (size_t)(bh * NTILE + kt) * TILE_B;
        const int fi  = (seg >> 1) * 4 + (dd >> 4);
        const int qd0 = (seg & 1) * 2;
        char* d0 = vbb + fi * 1024 + qd0 * 256 + (dd & 15) * 16;
        u32x4 o0 = {wv[0], wv[1], wv[2], wv[3]};
        u32x4 o1 = {wv[4], wv[5], wv[6], wv[7]};
        *(u32x4*)d0         = o0;
        *(u32x4*)(d0 + 256) = o1;
    }
}

// Main kernel: 256 threads = 4 FULLY INDEPENDENT waves; each wave pulls 32-q
// items from its group's queue. No LDS, no barriers. A/B register pipeline.
__global__ __launch_bounds__(256, 2)
void flash12(const float* __restrict__ Q, const int* __restrict__ EL,
             const float* __restrict__ MV, float* __restrict__ O,
             const char* __restrict__ Kbt, const char* __restrict__ Vbt,
             int* __restrict__ ticket) {
    const int t = threadIdx.x;

    // ---------- static phase: mean(V) rows above ceil32(el), 32-granular -----
    {
        const int bh0 = blockIdx.x & (NBH - 1);
        const int qb0 = (blockIdx.x >> 6) * 128;     // grid 1024: 16 chunks x 128q
        const int el32b = (EL[bh0 >> 4] + 31) & ~31;
        if (qb0 + 127 >= el32b) {
            float* Op = O + (size_t)bh0 * SQ * DH;
            const int c16 = t & 15, r0 = t >> 4;
            f32x4 mv = *(const f32x4*)(MV + bh0 * DH + c16 * 4);
            #pragma unroll
            for (int i = 0; i < 8; ++i) {
                const int row = qb0 + r0 + i * 16;
                if (row >= el32b)
                    *(f32x4*)(Op + (size_t)row * DH + c16 * 4) = mv;
            }
        }
    }

    // ---------- batch table, sorted descending by el (register network) ------
    int ka0 = EL[0], va0 = 0;
    int ka1 = EL[1], va1 = 1;
    int ka2 = EL[2], va2 = 2;
    int ka3 = EL[3], va3 = 3;
    #define CSWAP(x, y) if (ka##x < ka##y) { int tk_ = ka##x, tv_ = va##x; \
        ka##x = ka##y; va##x = va##y; ka##y = tk_; va##y = tv_; }
    CSWAP(0, 1) CSWAP(2, 3) CSWAP(0, 2) CSWAP(1, 3) CSWAP(1, 2)
    #undef CSWAP
    const int c0 = 2 * ((ka0 + 31) >> 5);    // items per (group, batch): 2 heads x qtiles
    const int c1 = 2 * ((ka1 + 31) >> 5);
    const int c2 = 2 * ((ka2 + 31) >> 5);
    const int c3 = 2 * ((ka3 + 31) >> 5);
    const int nvalid = c0 + c1 + c2 + c3;    // identical for every group

    const int grp = blockIdx.x & 7;          // blockIdx%8 ~ XCD (perf-only assumption)
    const int lane = t & 63, qd = lane >> 4, c = lane & 15;
    const float sc = 0.125f * 1.44269504f;   // 1/sqrt(D) * log2(e)

    for (;;) {
        int mytk = 0;
        if (lane == 0) mytk = atomicAdd(&ticket[grp], 1);
        const int it = __shfl(mytk, 0);
        if (it >= nvalid) break;

        // decode (largest batch first)
        int u = it, b, el;
        if (u < c0)             { b = va0; el = ka0; }
        else { u -= c0;
        if (u < c1)             { b = va1; el = ka1; }
        else { u -= c1;
        if (u < c2)             { b = va2; el = ka2; }
        else { u -= c2;           b = va3; el = ka3; } } }
        const int vb_ = (el + 31) >> 5;
        const int hh  = u / vb_;
        const int qt  = u - hh * vb_;
        const int bh  = b * 16 + grp + hh * 8;   // head%8 == grp -> L2 affinity
        const int qbase = qt * 32;

        const float* Qp = Q + (size_t)bh * SQ * DH;
        float*       Op = O + (size_t)bh * SQ * DH;
        const char*  Kt = Kbt + (size_t)bh * NTILE * TILE_B + (size_t)lane * 16;
        const char*  Vt = Vbt + (size_t)bh * NTILE * TILE_B + (size_t)lane * 16;

        // Q fragments (B-operand of S^T = K*Q^T); scale folded in
        bf16x8 qf[2][2];
        #pragma unroll
        for (int nt = 0; nt < 2; ++nt) {
            const int row = qbase + nt * 16 + c;
            #pragma unroll
            for (int kc = 0; kc < 2; ++kc) {
                const float* p = Qp + (size_t)row * DH + kc * 32 + qd * 8;
                f32x4 a  = *(const f32x4*)p;
                f32x4 bq = *(const f32x4*)(p + 4);
                u32x4 f;
                f[0] = pk2(a[0] * sc, a[1] * sc);
                f[1] = pk2(a[2] * sc, a[3] * sc);
                f[2] = pk2(bq[0] * sc, bq[1] * sc);
                f[3] = pk2(bq[2] * sc, bq[3] * sc);
                qf[nt][kc] = *(bf16x8*)&f;
            }
        }

        float l_[2] = {0.f, 0.f};
        f32x4 oacc[4][2];
        #pragma unroll
        for (int dt = 0; dt < 4; ++dt) {
            oacc[dt][0] = (f32x4){0.f, 0.f, 0.f, 0.f};
            oacc[dt][1] = (f32x4){0.f, 0.f, 0.f, 0.f};
        }

        const int nkt = (el + TK - 1) >> 6;

        bf16x8 kA[8], vA[8], kB[8], vB[8];

        #define LOAD_TILE(KB_, VB_, kt_) {                                     \
            const char* kb_ = Kt + (size_t)(kt_) * TILE_B;                     \
            const char* vp_ = Vt + (size_t)(kt_) * TILE_B;                     \
            _Pragma("unroll")                                                  \
            for (int i_ = 0; i_ < 8; ++i_)                                     \
                KB_[i_] = *(const bf16x8*)(kb_ + i_ * 1024);                   \
            _Pragma("unroll")                                                  \
            for (int i_ = 0; i_ < 8; ++i_)                                     \
                VB_[i_] = *(const bf16x8*)(vp_ + i_ * 1024);                   \
        }

        #define COMPUTE_TILE(KB_, VB_, kt_) {                                  \
            const int k0_ = (kt_) * TK;                                        \
            const bool strad_ = (k0_ + TK > el);                               \
            u32x4 pw_[2][2];                                                   \
            _Pragma("unroll")                                                  \
            for (int mt = 0; mt < 4; ++mt) {                                   \
                f32x4 s0 = (f32x4){0.f, 0.f, 0.f, 0.f};                        \
                s0 = __builtin_amdgcn_mfma_f32_16x16x32_bf16(KB_[mt*2],   qf[0][0], s0, 0, 0, 0); \
                s0 = __builtin_amdgcn_mfma_f32_16x16x32_bf16(KB_[mt*2+1], qf[0][1], s0, 0, 0, 0); \
                f32x4 s1 = (f32x4){0.f, 0.f, 0.f, 0.f};                        \
                s1 = __builtin_amdgcn_mfma_f32_16x16x32_bf16(KB_[mt*2],   qf[1][0], s1, 0, 0, 0); \
                s1 = __builtin_amdgcn_mfma_f32_16x16x32_bf16(KB_[mt*2+1], qf[1][1], s1, 0, 0, 0); \
                if (strad_) {                                                  \
                    _Pragma("unroll")                                          \
                    for (int r_ = 0; r_ < 4; ++r_)                             \
                        if (k0_ + mt * 16 + qd * 4 + r_ >= el) {               \
                            s0[r_] = -1e30f;                                   \
                            s1[r_] = -1e30f;                                   \
                        }                                                      \
                }                                                              \
                {                                                              \
                    const float p0 = __builtin_amdgcn_exp2f(s0[0]);            \
                    const float p1 = __builtin_amdgcn_exp2f(s0[1]);            \
                    const float p2 = __builtin_amdgcn_exp2f(s0[2]);            \
                    const float p3 = __builtin_amdgcn_exp2f(s0[3]);            \
                    l_[0] += (p0 + p1) + (p2 + p3);                            \
                    pw_[0][mt >> 1][(mt & 1) * 2]     = pk2(p0, p1);           \
                    pw_[0][mt >> 1][(mt & 1) * 2 + 1] = pk2(p2, p3);           \
                }                                                              \
                {                                                              \
                    const float p0 = __builtin_amdgcn_exp2f(s1[0]);            \
                    const float p1 = __builtin_amdgcn_exp2f(s1[1]);            \
                    const float p2 = __builtin_amdgcn_exp2f(s1[2]);            \
                    const float p3 = __builtin_amdgcn_exp2f(s1[3]);            \
                    l_[1] += (p0 + p1) + (p2 + p3);                            \
                    pw_[1][mt >> 1][(mt & 1) * 2]     = pk2(p0, p1);           \
                    pw_[1][mt >> 1][(mt & 1) * 2 + 1] = pk2(p2, p3);           \
                }                                                              \
            }                                                                  \
            _Pragma("unroll")                                                  \
            for (int kc = 0; kc < 2; ++kc) {                                   \
                bf16x8 pb0 = *(bf16x8*)&pw_[0][kc];                            \
                bf16x8 pb1 = *(bf16x8*)&pw_[1][kc];                            \
                _Pragma("unroll")                                              \
                for (int dt = 0; dt < 4; ++dt) {                               \
                    oacc[dt][0] = __builtin_amdgcn_mfma_f32_16x16x32_bf16(VB_[kc*4+dt], pb0, oacc[dt][0], 0, 0, 0); \
                    oacc[dt][1] = __builtin_amdgcn_mfma_f32_16x16x32_bf16(VB_[kc*4+dt], pb1, oacc[dt][1], 0, 0, 0); \
                }                                                              \
            }                                                                  \
        }

        // prologue: tiles 0 (A) and 1 (B) in flight
        LOAD_TILE(kA, vA, 0)
        if (nkt > 1) LOAD_TILE(kB, vB, 1)

        for (int kt = 0; kt < nkt; kt += 2) {
            COMPUTE_TILE(kA, vA, kt)
            if (kt + 2 < nkt) LOAD_TILE(kA, vA, kt + 2)
            if (kt + 1 >= nkt) break;
            COMPUTE_TILE(kB, vB, kt + 1)
            if (kt + 3 < nkt) LOAD_TILE(kB, vB, kt + 3)
        }

        #undef LOAD_TILE
        #undef COMPUTE_TILE

        // denominators: cross-lane combine over qd groups (same query col c)
        #pragma unroll
        for (int nt = 0; nt < 2; ++nt) {
            l_[nt] += __shfl_xor(l_[nt], 16);
            l_[nt] += __shfl_xor(l_[nt], 32);
        }

        #pragma unroll
        for (int nt = 0; nt < 2; ++nt) {
            const int qrow = qbase + nt * 16 + c;
            if (qrow < el) {
                const float inv = 1.0f / l_[nt];
                #pragma unroll
                for (int dt = 0; dt < 4; ++dt) {
                    f32x4 o = oacc[dt][nt];
                    o[0] *= inv; o[1] *= inv; o[2] *= inv; o[3] *= inv;
                    *(f32x4*)(Op + (size_t)qrow * DH + dt * 16 + qd * 4) = o;
                }
            } else {
                #pragma unroll
                for (int dt = 0; dt < 4; ++dt)
                    *(f32x4*)(Op + (size_t)qrow * DH + dt * 16 + qd * 4) =
                        *(const f32x4*)(MV + bh * DH + dt * 16 + qd * 4);
            }
        }
    }
}

// ============================================================================
// FALLBACK PATH (proven R5 kernels, used when ws_size < ~33.6 MB)
// ============================================================================

__global__ __launch_bounds__(256)
void meanv_k(const float* __restrict__ V, float* __restrict__ MV) {
    const int bh  = blockIdx.x >> 4;
    const int seg = blockIdx.x & 15;
    const float* vp = V + ((size_t)bh * SQ + (size_t)seg * 128) * DH;
    const int c = threadIdx.x & 15;
    const int r = threadIdx.x >> 4;
    const float* p = vp + (size_t)r * DH + c * 4;
    f32x4 s0 = *(const f32x4*)(p);
    f32x4 s1 = *(const f32x4*)(p + 16 * DH);
    f32x4 s2 = *(const f32x4*)(p + 32 * DH);
    f32x4 s3 = *(const f32x4*)(p + 48 * DH);
    s0 += *(const f32x4*)(p + 64 * DH);
    s1 += *(const f32x4*)(p + 80 * DH);
    s2 += *(const f32x4*)(p + 96 * DH);
    s3 += *(const f32x4*)(p + 112 * DH);
    f32x4 s = (s0 + s1) + (s2 + s3);
    __shared__ f32x4 red[16][16];
    red[r][c] = s;
    __syncthreads();
    if (threadIdx.x < 16) {
        f32x4 a = red[0][threadIdx.x];
        #pragma unroll
        for (int j = 1; j < 16; ++j) a += red[j][threadIdx.x];
        const float inv = 1.0f / (float)SQ;
        atomicAdd(&MV[bh * DH + threadIdx.x * 4 + 0], a[0] * inv);
        atomicAdd(&MV[bh * DH + threadIdx.x * 4 + 1], a[1] * inv);
        atomicAdd(&MV[bh * DH + threadIdx.x * 4 + 2], a[2] * inv);
        atomicAdd(&MV[bh * DH + threadIdx.x * 4 + 3], a[3] * inv);
    }
}

__global__ __launch_bounds__(256, 3)
void flash5(const float* __restrict__ Q, const float* __restrict__ K,
            const float* __restrict__ V, const int* __restrict__ EL,
            const float* __restrict__ MV, float* __restrict__ O,
            int* __restrict__ ticket) {
    const int t = threadIdx.x;
    {
        const int bh0    = blockIdx.x & (NBH - 1);
        const int qbase0 = (blockIdx.x >> 6) * 128;
        const int elb    = EL[bh0 >> 4];
        if (qbase0 >= elb) {
            float* Op = O + (size_t)bh0 * SQ * DH;
            const int c16 = t & 15, r0 = t >> 4;
            f32x4 mv = *(const f32x4*)(MV + bh0 * DH + c16 * 4);
            #pragma unroll
            for (int i = 0; i < 8; ++i)
                *(f32x4*)(Op + (size_t)(qbase0 + r0 + i * 16) * DH + c16 * 4) = mv;
        }
    }

    const int el0 = EL[0], el1 = EL[1], el2 = EL[2], el3 = EL[3];
    const int v0 = (el0 + 127) >> 7, v1 = (el1 + 127) >> 7;
    const int v2 = (el2 + 127) >> 7, v3 = (el3 + 127) >> 7;
    const int n0 = 16 * v0, n1 = n0 + 16 * v1, n2 = n1 + 16 * v2;
    const int nvalid = n2 + 16 * v3;

    __shared__ short Kb[TK][LDE];
    __shared__ short Vt[DH][LDE];
    __shared__ short Pl[4][32][LDE];
    __shared__ int item_s;

    const int wq = t >> 6, lane = t & 63, qd = lane >> 4, c = lane & 15;
    const int ksrow = t >> 2;
    const int ksdc  = t & 3;
    const int vpair = t & 31;
    const int vdg   = t >> 5;

    for (;;) {
        if (t == 0) item_s = atomicAdd(ticket, 1);
        __syncthreads();
        const int it = item_s;
        if (it >= nvalid) break;

        int b, u, vb, el;
        if      (it < n0) { b = 0; u = it;      vb = v0; el = el0; }
        else if (it < n1) { b = 1; u = it - n0; vb = v1; el = el1; }
        else if (it < n2) { b = 2; u = it - n1; vb = v2; el = el2; }
        else              { b = 3; u = it - n2; vb = v3; el = el3; }
        const int head  = u / vb;
        const int qt    = u - head * vb;
        const int bh    = b * 16 + head;
        const int qbase = qt * 128;

        const size_t base = (size_t)bh * SQ * DH;
        const float* Qp = Q + base;
        const float* Kp = K + base;
        const float* Vp = V + base;
        float* Op = O + base;

        const float sc = 0.125f * 1.44269504f;
        bf16x8 qf[2][2];
        #pragma unroll
        for (int nt = 0; nt < 2; ++nt) {
            const int row = qbase + wq * 32 + nt * 16 + c;
            #pragma unroll
            for (int kc = 0; kc < 2; ++kc) {
                const float* p = Qp + (size_t)row * DH + kc * 32 + qd * 8;
                f32x4 a  = *(const f32x4*)p;
                f32x4 bb = *(const f32x4*)(p + 4);
                u32x4 f;
                f[0] = pk2(a[0] * sc, a[1] * sc);
                f[1] = pk2(a[2] * sc, a[3] * sc);
                f[2] = pk2(bb[0] * sc, bb[1] * sc);
                f[3] = pk2(bb[2] * sc, bb[3] * sc);
                qf[nt][kc] = *(bf16x8*)&f;
            }
        }

        float l_[2] = {0.f, 0.f};
        f32x4 oacc[4][2];
        #pragma unroll
        for (int dt = 0; dt < 4; ++dt)
            #pragma unroll
            for (int nt = 0; nt < 2; ++nt)
                oacc[dt][nt] = (f32x4){0.f, 0.f, 0.f, 0.f};

        const int nkt = (el + TK - 1) / TK;

        f32x4 kg0, kg1, kg2, kg3, vg0, vg1, vg2, vg3;
        {
            const float* kp = Kp + (size_t)ksrow * DH + ksdc * 16;
            kg0 = *(const f32x4*)kp;
            kg1 = *(const f32x4*)(kp + 4);
            kg2 = *(const f32x4*)(kp + 8);
            kg3 = *(const f32x4*)(kp + 12);
            const float* vp0 = Vp + (size_t)(2 * vpair) * DH + vdg * 8;
            vg0 = *(const f32x4*)vp0;
            vg1 = *(const f32x4*)(vp0 + 4);
            vg2 = *(const f32x4*)(vp0 + DH);
            vg3 = *(const f32x4*)(vp0 + DH + 4);
        }

        for (int kt = 0; kt < nkt; ++kt) {
            const int k0 = kt * TK;

            __syncthreads();
            {
                u32x4 w0, w1;
                w0[0] = pk2(kg0[0], kg0[1]); w0[1] = pk2(kg0[2], kg0[3]);
                w0[2] = pk2(kg1[0], kg1[1]); w0[3] = pk2(kg1[2], kg1[3]);
                w1[0] = pk2(kg2[0], kg2[1]); w1[1] = pk2(kg2[2], kg2[3]);
                w1[2] = pk2(kg3[0], kg3[1]); w1[3] = pk2(kg3[2], kg3[3]);
                *(u32x4*)&Kb[ksrow][ksdc * 16]     = w0;
                *(u32x4*)&Kb[ksrow][ksdc * 16 + 8] = w1;
            }
            {
                #pragma unroll
                for (int i = 0; i < 4; ++i) {
                    *(unsigned int*)&Vt[vdg * 8 + i][2 * vpair]     = pk2(vg0[i], vg2[i]);
                    *(unsigned int*)&Vt[vdg * 8 + 4 + i][2 * vpair] = pk2(vg1[i], vg3[i]);
                }
            }
            __syncthreads();

            if (kt + 1 < nkt) {
                const int kn = k0 + TK;
                const float* kp = Kp + (size_t)(kn + ksrow) * DH + ksdc * 16;
                kg0 = *(const f32x4*)kp;
                kg1 = *(const f32x4*)(kp + 4);
                kg2 = *(const f32x4*)(kp + 8);
                kg3 = *(const f32x4*)(kp + 12);
                const float* vp0 = Vp + (size_t)(kn + 2 * vpair) * DH + vdg * 8;
                vg0 = *(const f32x4*)vp0;
                vg1 = *(const f32x4*)(vp0 + 4);
                vg2 = *(const f32x4*)(vp0 + DH);
                vg3 = *(const f32x4*)(vp0 + DH + 4);
            }

            f32x4 st[4][2];
            #pragma unroll
            for (int mt = 0; mt < 4; ++mt) {
                bf16x8 a0 = *(const bf16x8*)&Kb[mt * 16 + c][qd * 8];
                bf16x8 a1 = *(const bf16x8*)&Kb[mt * 16 + c][32 + qd * 8];
                #pragma unroll
                for (int nt = 0; nt < 2; ++nt) {
                    f32x4 acc = (f32x4){0.f, 0.f, 0.f, 0.f};
                    acc = __builtin_amdgcn_mfma_f32_16x16x32_bf16(a0, qf[nt][0], acc, 0, 0, 0);
                    acc = __builtin_amdgcn_mfma_f32_16x16x32_bf16(a1, qf[nt][1], acc, 0, 0, 0);
                    st[mt][nt] = acc;
                }
            }

            if (k0 + TK > el) {
                #pragma unroll
                for (int mt = 0; mt < 4; ++mt)
                    #pragma unroll
                    for (int r = 0; r < 4; ++r)
                        if (k0 + mt * 16 + qd * 4 + r >= el) {
                            st[mt][0][r] = -1e30f;
                            st[mt][1][r] = -1e30f;
                        }
            }

            #pragma unroll
            for (int nt = 0; nt < 2; ++nt) {
                #pragma unroll
                for (int mt = 0; mt < 4; ++mt) {
                    const float p0 = exp2f(st[mt][nt][0]);
                    const float p1 = exp2f(st[mt][nt][1]);
                    const float p2 = exp2f(st[mt][nt][2]);
                    const float p3 = exp2f(st[mt][nt][3]);
                    l_[nt] += (p0 + p1) + (p2 + p3);
                    u32x2 pw;
                    pw[0] = pk2(p0, p1);
                    pw[1] = pk2(p2, p3);
                    *(u32x2*)&Pl[wq][nt * 16 + c][mt * 16 + qd * 4] = pw;
                }
            }

            #pragma unroll
            for (int kc = 0; kc < 2; ++kc) {
                bf16x8 pb0 = *(const bf16x8*)&Pl[wq][c][kc * 32 + qd * 8];
                bf16x8 pb1 = *(const bf16x8*)&Pl[wq][16 + c][kc * 32 + qd * 8];
                #pragma unroll
                for (int dt = 0; dt < 4; ++dt) {
                    bf16x8 vf = *(const bf16x8*)&Vt[dt * 16 + c][kc * 32 + qd * 8];
                    oacc[dt][0] = __builtin_amdgcn_mfma_f32_16x16x32_bf16(vf, pb0, oacc[dt][0], 0, 0, 0);
                    oacc[dt][1] = __builtin_amdgcn_mfma_f32_16x16x32_bf16(vf, pb1, oacc[dt][1], 0, 0, 0);
                }
            }
        }

        #pragma unroll
        for (int nt = 0; nt < 2; ++nt) {
            l_[nt] += __shfl_xor(l_[nt], 16);
            l_[nt] += __shfl_xor(l_[nt], 32);
        }

        #pragma unroll
        for (int nt = 0; nt < 2; ++nt) {
            const int row = qbase + wq * 32 + nt * 16 + c;
            if (row < el) {
                const float inv = 1.0f / l_[nt];
                #pragma unroll
                for (int dt = 0; dt < 4; ++dt) {
                    f32x4 o = oacc[dt][nt];
                    o[0] *= inv; o[1] *= inv; o[2] *= inv; o[3] *= inv;
                    *(f32x4*)(Op + (size_t)row * DH + dt * 16 + qd * 4) = o;
                }
            } else {
                #pragma unroll
                for (int dt = 0; dt < 4; ++dt) {
                    f32x4 mv = *(const f32x4*)(MV + bh * DH + dt * 16 + qd * 4);
                    *(f32x4*)(Op + (size_t)row * DH + dt * 16 + qd * 4) = mv;
                }
            }
        }
    }
}

// ============================================================================

extern "C" void kernel_launch(void* const* d_in, const int* in_sizes, int n_in,
                              void* d_out, int out_size, void* d_ws, size_t ws_size,
                              hipStream_t stream) {
    const float* q  = (const float*)d_in[0];
    const float* k  = (const float*)d_in[1];
    const float* v  = (const float*)d_in[2];
    const int*   el = (const int*)d_in[3];
    float* out = (float*)d_out;

    const size_t kbt_bytes = (size_t)NBH * NTILE * TILE_B;      // 16 MiB
    const size_t needed    = 65536 + 2 * kbt_bytes;             // ~33.6 MiB

    if (ws_size >= needed) {
        // new path: fragment-ordered prepass + wave-independent affinity flash
        float* mv  = (float*)d_ws;
        int*   tk  = (int*)((char*)d_ws + 16384);               // 8 group tickets
        char*  kbt = (char*)d_ws + 65536;
        char*  vbt = kbt + kbt_bytes;

        hipMemsetAsync(d_ws, 0, 65536, stream);
        convkv<<<dim3(NBH * NTILE), dim3(256), 0, stream>>>(k, v, el, mv, kbt, vbt);
        flash12<<<dim3(NBH * 16), dim3(256), 0, stream>>>(q, el, mv, out, kbt, vbt, tk);
    } else {
        // fallback: proven R5 path
        float* mv = (float*)d_ws;
        int*   tk = (int*)((char*)d_ws + NBH * DH * sizeof(float));

        hipMemsetAsync(d_ws, 0, NBH * DH * sizeof(float) + 64, stream);
        meanv_k<<<dim3(NBH * 16), dim3(256), 0, stream>>>(v, mv);
        flash5<<<dim3(NBH * (SQ / 128)), dim3(256), 0, stream>>>(q, k, v, el, mv, out, tk);
    }
}

// Round 8
// 192.532 us; speedup vs baseline: 1.1574x; 1.1574x over previous
//
#include <hip/hip_runtime.h>
#include <hip/hip_bf16.h>

// InnocentAttention: B=4 H=16 S=2048 D=64, fp32 in/out, per-batch event_length mask.
//
// R13 = R11 with ONE change: the two k-loop barriers are raw s_barrier
// (asm volatile, memory clobber) instead of __syncthreads(). HIP's
// __syncthreads() always emits s_waitcnt vmcnt(0) before s_barrier, which
// drained the 2-tile prefetch EVERY tile in R9-R11 -- the counted VMCNT(4)
// was a no-op, and per-tile cost == full L3 load latency (~2us x 32 tiles
// == the stubborn ~75us plateau). Raw s_barrier keeps 2 future tiles in
// flight; VMCNT(4) waits only for own tile-kt copies (collective via the
// barrier). Everything else identical to R11: XCD-affinity queues, 256-q
// items, fragment-ordered workspace, 3-slot ring.
// Falls back to the proven R5 path when ws_size < ~33.6 MB.

#define SQ 2048
#define DH 64
#define NBH 64
#define TK 64
#define NTILE 32           // SQ / TK
#define TILE_B 8192        // TK * DH * 2 bytes (bf16)
#define LDE 72             // fallback-path padded LDS stride
#define LVP 68             // prepass V-stage stride

typedef __attribute__((ext_vector_type(4))) float f32x4;
typedef __attribute__((ext_vector_type(8))) short bf16x8;
typedef __attribute__((ext_vector_type(4))) unsigned int u32x4;
typedef __attribute__((ext_vector_type(2))) unsigned int u32x2;

#define VMCNT(n) asm volatile("s_waitcnt vmcnt(" #n ")" ::: "memory")
#define RAW_BARRIER() asm volatile("s_barrier" ::: "memory")

__device__ __forceinline__ unsigned int pk2(float lo, float hi) {
    // v_cvt_pk_bf16_f32 on gfx950 (RNE), lo -> low 16 bits
    __hip_bfloat162 h = __float22bfloat162_rn(float2{lo, hi});
    union { __hip_bfloat162 h; unsigned int u; } c; c.h = h;
    return c.u;
}

__device__ __forceinline__ float bfu16_to_f(unsigned short s) {
    union { unsigned int u; float f; } c; c.u = ((unsigned int)s) << 16;
    return c.f;
}

__device__ __forceinline__ void async_cp16(const void* g, void* l) {
    // global -> LDS direct DMA, 16B/lane; LDS dest = wave-uniform base + lane*16
    __builtin_amdgcn_global_load_lds(
        (const __attribute__((address_space(1))) unsigned int*)g,
        (__attribute__((address_space(3))) unsigned int*)l, 16, 0, 0);
}

// ============================================================================
// NEW PATH
// ============================================================================

// Prepass (validated R8-R11): one block per (bh, 64-key tile). Fragment-ordered:
//  K tile: line fi = mt*2+half (1KB); lane l=(qd*16+c): 16B =
//          K[key=mt*16+c][d = half*32+qd*8 .. +7] bf16.
//  V tile: line fi = kc*4+dt; lane l: element j =
//          V[key = kc*32 + (j>>2)*16 + qd*4 + (j&3)][d = dt*16+c]  (pi order)
//  MV[bh][d] += mean contribution of this tile's 64 V rows (atomic)
__global__ __launch_bounds__(256)
void convkv(const float* __restrict__ K, const float* __restrict__ V,
            const int* __restrict__ EL, float* __restrict__ MV,
            char* __restrict__ Kbt, char* __restrict__ Vbt) {
    const int bh = blockIdx.x >> 5;
    const int kt = blockIdx.x & 31;
    const int k0 = kt * TK;
    const int el = EL[bh >> 4];
    const int t = threadIdx.x;
    const int r  = t >> 2;      // key row 0..63
    const int dc = t & 3;       // 16-d chunk

    __shared__ short LV[64][LVP];

    // stage V row (bf16) into LDS for transpose + mean
    {
        const float* vp = V + ((size_t)bh * SQ + k0 + r) * DH + dc * 16;
        f32x4 a = *(const f32x4*)vp;
        f32x4 b = *(const f32x4*)(vp + 4);
        f32x4 c2 = *(const f32x4*)(vp + 8);
        f32x4 d2 = *(const f32x4*)(vp + 12);
        u32x4 w0, w1;
        w0[0] = pk2(a[0], a[1]);  w0[1] = pk2(a[2], a[3]);
        w0[2] = pk2(b[0], b[1]);  w0[3] = pk2(b[2], b[3]);
        w1[0] = pk2(c2[0], c2[1]); w1[1] = pk2(c2[2], c2[3]);
        w1[2] = pk2(d2[0], d2[1]); w1[3] = pk2(d2[2], d2[3]);
        *(u32x4*)&LV[r][dc * 16]     = w0;
        *(u32x4*)&LV[r][dc * 16 + 8] = w1;
    }

    // K convert (valid tiles only) -> fragment-ordered lines
    if (k0 < el) {
        const float* kp = K + ((size_t)bh * SQ + k0 + r) * DH + dc * 16;
        f32x4 a = *(const f32x4*)kp;
        f32x4 b = *(const f32x4*)(kp + 4);
        f32x4 c2 = *(const f32x4*)(kp + 8);
        f32x4 d2 = *(const f32x4*)(kp + 12);
        u32x4 w0, w1;
        w0[0] = pk2(a[0], a[1]);  w0[1] = pk2(a[2], a[3]);
        w0[2] = pk2(b[0], b[1]);  w0[3] = pk2(b[2], b[3]);
        w1[0] = pk2(c2[0], c2[1]); w1[1] = pk2(c2[2], c2[3]);
        w1[2] = pk2(d2[0], d2[1]); w1[3] = pk2(d2[2], d2[3]);
        char* kb = Kbt + (size_t)(bh * NTILE + kt) * TILE_B;
        const int fi  = (r >> 4) * 2 + (dc >> 1);
        const int qd0 = (dc & 1) * 2;
        char* d0 = kb + fi * 1024 + qd0 * 256 + (r & 15) * 16;
        *(u32x4*)d0         = w0;
        *(u32x4*)(d0 + 256) = w1;
    }

    __syncthreads();

    // transpose-read V in pi order + mean partial
    const int dd  = t >> 2;     // d row 0..63
    const int seg = t & 3;      // 16-pos segment
    float msum = 0.f;
    unsigned int wv[8];
    #pragma unroll
    for (int i = 0; i < 8; ++i) {
        const int pos = seg * 16 + 2 * i;
        const int key = (pos & ~31) | ((pos & 4) << 2) | ((pos & 24) >> 1) | (pos & 3);
        const unsigned short s0 = (unsigned short)LV[key][dd];
        const unsigned short s1 = (unsigned short)LV[key + 1][dd];
        msum += bfu16_to_f(s0) + bfu16_to_f(s1);
        wv[i] = (unsigned int)s0 | ((unsigned int)s1 << 16);
    }
    msum += __shfl_xor(msum, 1);
    msum += __shfl_xor(msum, 2);
    if (seg == 0) atomicAdd(&MV[bh * DH + dd], msum * (1.0f / (float)SQ));

    if (k0 < el) {
        char* vbb = Vbt + (size_t)(bh * NTILE + kt) * TILE_B;
        const int fi  = (seg >> 1) * 4 + (dd >> 4);
        const int qd0 = (seg & 1) * 2;
        char* d0 = vbb + fi * 1024 + qd0 * 256 + (dd & 15) * 16;
        u32x4 o0 = {wv[0], wv[1], wv[2], wv[3]};
        u32x4 o1 = {wv[4], wv[5], wv[6], wv[7]};
        *(u32x4*)d0         = o0;
        *(u32x4*)(d0 + 256) = o1;
    }
}

// Main kernel: 512 threads = 8 waves x 32 queries = 256-q items.
// Per-XCD ticket queues, 3-slot ring, counted vmcnt + RAW barriers (no drain).
__global__ __launch_bounds__(512, 4)
void flash13(const float* __restrict__ Q, const int* __restrict__ EL,
             const float* __restrict__ MV, float* __restrict__ O,
             const char* __restrict__ Kbt, const char* __restrict__ Vbt,
             int* __restrict__ ticket) {
    const int t = threadIdx.x;

    // ---------- static phase: mean(V) rows for own fully-masked q-block ------
    {
        const int bh0 = blockIdx.x & (NBH - 1);
        const int qb0 = (blockIdx.x >> 6) * 256;     // grid 512: 8 chunks of 256q
        const int elb = EL[bh0 >> 4];
        if (qb0 >= elb) {
            float* Op = O + (size_t)bh0 * SQ * DH;
            const int c16 = t & 15, r0 = t >> 4;     // r0 0..31
            f32x4 mv = *(const f32x4*)(MV + bh0 * DH + c16 * 4);
            #pragma unroll
            for (int i = 0; i < 8; ++i)
                *(f32x4*)(Op + (size_t)(qb0 + r0 + i * 32) * DH + c16 * 4) = mv;
        }
    }

    // ---------- batch table, sorted descending by el (register network) ------
    int ka0 = EL[0], va0 = 0;
    int ka1 = EL[1], va1 = 1;
    int ka2 = EL[2], va2 = 2;
    int ka3 = EL[3], va3 = 3;
    #define CSWAP(x, y) if (ka##x < ka##y) { int tk_ = ka##x, tv_ = va##x; \
        ka##x = ka##y; va##x = va##y; ka##y = tk_; va##y = tv_; }
    CSWAP(0, 1) CSWAP(2, 3) CSWAP(0, 2) CSWAP(1, 3) CSWAP(1, 2)
    #undef CSWAP
    const int c0 = 2 * ((ka0 + 255) >> 8);   // items per (group, batch), sorted order
    const int c1 = 2 * ((ka1 + 255) >> 8);
    const int c2 = 2 * ((ka2 + 255) >> 8);
    const int c3 = 2 * ((ka3 + 255) >> 8);
    const int nvalid = c0 + c1 + c2 + c3;    // identical for every group

    __shared__ char KB[3 * TILE_B];
    __shared__ char VB[3 * TILE_B];
    __shared__ int item_s;

    const int grp = blockIdx.x & 7;          // blockIdx%8 ~ XCD (perf-only assumption)
    const int wq = t >> 6, lane = t & 63, qd = lane >> 4, c = lane & 15;
    const float sc = 0.125f * 1.44269504f;   // 1/sqrt(D) * log2(e)

    for (;;) {
        if (t == 0) item_s = atomicAdd(&ticket[grp], 1);
        __syncthreads();                     // item boundary: full drain is fine here
        const int it = item_s;
        if (it >= nvalid) break;

        // decode (largest batch first)
        int u = it, b, el;
        if (u < c0)             { b = va0; el = ka0; }
        else { u -= c0;
        if (u < c1)             { b = va1; el = ka1; }
        else { u -= c1;
        if (u < c2)             { b = va2; el = ka2; }
        else { u -= c2;           b = va3; el = ka3; } } }
        const int vb_ = (el + 255) >> 8;
        const int hh  = u / vb_;
        const int qt  = u - hh * vb_;
        const int bh  = b * 16 + grp + hh * 8;   // head%8 == grp -> L2 affinity
        const int qbase = qt * 256;

        const float* Qp = Q + (size_t)bh * SQ * DH;
        float*       Op = O + (size_t)bh * SQ * DH;
        const char*  Kt = Kbt + (size_t)bh * NTILE * TILE_B + t * 16;
        const char*  Vt = Vbt + (size_t)bh * NTILE * TILE_B + t * 16;
        char* const  kdst = KB + wq * 1024;
        char* const  vdst = VB + wq * 1024;

        const int nkt = (el + TK - 1) >> 6;

        // prologue: tiles 0 and 1 in flight (2 VMEM instr per wave per tile)
        async_cp16(Kt, kdst);
        async_cp16(Vt, vdst);
        if (nkt > 1) {
            async_cp16(Kt + TILE_B, kdst + TILE_B);
            async_cp16(Vt + TILE_B, vdst + TILE_B);
        }

        // Q fragments (B-operand of S^T = K*Q^T); scale folded in
        bf16x8 qf[2][2];
        #pragma unroll
        for (int nt = 0; nt < 2; ++nt) {
            const int row = qbase + wq * 32 + nt * 16 + c;
            #pragma unroll
            for (int kc = 0; kc < 2; ++kc) {
                const float* p = Qp + (size_t)row * DH + kc * 32 + qd * 8;
                f32x4 a  = *(const f32x4*)p;
                f32x4 bq = *(const f32x4*)(p + 4);
                u32x4 f;
                f[0] = pk2(a[0] * sc, a[1] * sc);
                f[1] = pk2(a[2] * sc, a[3] * sc);
                f[2] = pk2(bq[0] * sc, bq[1] * sc);
                f[3] = pk2(bq[2] * sc, bq[3] * sc);
                qf[nt][kc] = *(bf16x8*)&f;
            }
        }

        float l_[2] = {0.f, 0.f};
        f32x4 oacc[4][2];
        #pragma unroll
        for (int dt = 0; dt < 4; ++dt) {
            oacc[dt][0] = (f32x4){0.f, 0.f, 0.f, 0.f};
            oacc[dt][1] = (f32x4){0.f, 0.f, 0.f, 0.f};
        }

        for (int kt = 0; kt < nkt; ++kt) {
            const int s = kt % 3;

            // all waves finished computing tile kt-1 -> its ring slot reusable.
            // RAW barrier: does NOT drain vmcnt -- prefetches stay in flight.
            RAW_BARRIER();
            if (kt + 2 < nkt) {
                const int s2 = (kt + 2) % 3;
                async_cp16(Kt + (size_t)(kt + 2) * TILE_B, kdst + s2 * TILE_B);
                async_cp16(Vt + (size_t)(kt + 2) * TILE_B, vdst + s2 * TILE_B);
            }
            // counted wait: own tile-kt copies done; 2 future tiles stay in flight
            if      (kt + 2 < nkt) VMCNT(4);
            else if (kt + 1 < nkt) VMCNT(2);
            else                   VMCNT(0);
            RAW_BARRIER();                   // everyone's tile-kt lines visible

            const char* Kb = KB + s * TILE_B + lane * 16;
            const char* Vb = VB + s * TILE_B + lane * 16;

            // ---- S^T = K * Q^T : contiguous fragment-line reads ----
            f32x4 st[4][2];
            __builtin_amdgcn_s_setprio(1);
            #pragma unroll
            for (int mt = 0; mt < 4; ++mt) {
                bf16x8 a0 = *(const bf16x8*)(Kb + (mt * 2) * 1024);
                bf16x8 a1 = *(const bf16x8*)(Kb + (mt * 2 + 1) * 1024);
                #pragma unroll
                for (int nt = 0; nt < 2; ++nt) {
                    f32x4 acc = (f32x4){0.f, 0.f, 0.f, 0.f};
                    acc = __builtin_amdgcn_mfma_f32_16x16x32_bf16(a0, qf[nt][0], acc, 0, 0, 0);
                    acc = __builtin_amdgcn_mfma_f32_16x16x32_bf16(a1, qf[nt][1], acc, 0, 0, 0);
                    st[mt][nt] = acc;
                }
            }
            __builtin_amdgcn_s_setprio(0);

            const int k0 = kt * TK;
            if (k0 + TK > el) {    // straddling tile: mask invalid keys
                #pragma unroll
                for (int mt = 0; mt < 4; ++mt)
                    #pragma unroll
                    for (int r = 0; r < 4; ++r)
                        if (k0 + mt * 16 + qd * 4 + r >= el) {
                            st[mt][0][r] = -1e30f;
                            st[mt][1][r] = -1e30f;
                        }
            }

            // ---- p = exp2(s); pack in-register (pi order == lane's own keys) ----
            u32x4 pw[2][2];
            #pragma unroll
            for (int nt = 0; nt < 2; ++nt) {
                #pragma unroll
                for (int mt = 0; mt < 4; ++mt) {
                    const float p0 = __builtin_amdgcn_exp2f(st[mt][nt][0]);
                    const float p1 = __builtin_amdgcn_exp2f(st[mt][nt][1]);
                    const float p2 = __builtin_amdgcn_exp2f(st[mt][nt][2]);
                    const float p3 = __builtin_amdgcn_exp2f(st[mt][nt][3]);
                    l_[nt] += (p0 + p1) + (p2 + p3);
                    pw[nt][mt >> 1][(mt & 1) * 2]     = pk2(p0, p1);
                    pw[nt][mt >> 1][(mt & 1) * 2 + 1] = pk2(p2, p3);
                }
            }

            // ---- O^T += V^T * P^T : V lines pi-permuted, P in-register ----
            __builtin_amdgcn_s_setprio(1);
            #pragma unroll
            for (int kc = 0; kc < 2; ++kc) {
                bf16x8 pb0 = *(bf16x8*)&pw[0][kc];
                bf16x8 pb1 = *(bf16x8*)&pw[1][kc];
                #pragma unroll
                for (int dt = 0; dt < 4; ++dt) {
                    bf16x8 vf = *(const bf16x8*)(Vb + (kc * 4 + dt) * 1024);
                    oacc[dt][0] = __builtin_amdgcn_mfma_f32_16x16x32_bf16(vf, pb0, oacc[dt][0], 0, 0, 0);
                    oacc[dt][1] = __builtin_amdgcn_mfma_f32_16x16x32_bf16(vf, pb1, oacc[dt][1], 0, 0, 0);
                }
            }
            __builtin_amdgcn_s_setprio(0);
        }

        // denominators: cross-lane combine over qd groups (same query col c)
        #pragma unroll
        for (int nt = 0; nt < 2; ++nt) {
            l_[nt] += __shfl_xor(l_[nt], 16);
            l_[nt] += __shfl_xor(l_[nt], 32);
        }

        #pragma unroll
        for (int nt = 0; nt < 2; ++nt) {
            const int qrow = qbase + wq * 32 + nt * 16 + c;
            if (qrow < el) {
                const float inv = 1.0f / l_[nt];
                #pragma unroll
                for (int dt = 0; dt < 4; ++dt) {
                    f32x4 o = oacc[dt][nt];
                    o[0] *= inv; o[1] *= inv; o[2] *= inv; o[3] *= inv;
                    *(f32x4*)(Op + (size_t)qrow * DH + dt * 16 + qd * 4) = o;
                }
            } else {
                #pragma unroll
                for (int dt = 0; dt < 4; ++dt)
                    *(f32x4*)(Op + (size_t)qrow * DH + dt * 16 + qd * 4) =
                        *(const f32x4*)(MV + bh * DH + dt * 16 + qd * 4);
            }
        }
    }
}

// ============================================================================
// FALLBACK PATH (proven R5 kernels, used when ws_size < ~33.6 MB)
// ============================================================================

__global__ __launch_bounds__(256)
void meanv_k(const float* __restrict__ V, float* __restrict__ MV) {
    const int bh  = blockIdx.x >> 4;
    const int seg = blockIdx.x & 15;
    const float* vp = V + ((size_t)bh * SQ + (size_t)seg * 128) * DH;
    const int c = threadIdx.x & 15;
    const int r = threadIdx.x >> 4;
    const float* p = vp + (size_t)r * DH + c * 4;
    f32x4 s0 = *(const f32x4*)(p);
    f32x4 s1 = *(const f32x4*)(p + 16 * DH);
    f32x4 s2 = *(const f32x4*)(p + 32 * DH);
    f32x4 s3 = *(const f32x4*)(p + 48 * DH);
    s0 += *(const f32x4*)(p + 64 * DH);
    s1 += *(const f32x4*)(p + 80 * DH);
    s2 += *(const f32x4*)(p + 96 * DH);
    s3 += *(const f32x4*)(p + 112 * DH);
    f32x4 s = (s0 + s1) + (s2 + s3);
    __shared__ f32x4 red[16][16];
    red[r][c] = s;
    __syncthreads();
    if (threadIdx.x < 16) {
        f32x4 a = red[0][threadIdx.x];
        #pragma unroll
        for (int j = 1; j < 16; ++j) a += red[j][threadIdx.x];
        const float inv = 1.0f / (float)SQ;
        atomicAdd(&MV[bh * DH + threadIdx.x * 4 + 0], a[0] * inv);
        atomicAdd(&MV[bh * DH + threadIdx.x * 4 + 1], a[1] * inv);
        atomicAdd(&MV[bh * DH + threadIdx.x * 4 + 2], a[2] * inv);
        atomicAdd(&MV[bh * DH + threadIdx.x * 4 + 3], a[3] * inv);
    }
}

__global__ __launch_bounds__(256, 3)
void flash5(const float* __restrict__ Q, const float* __restrict__ K,
            const float* __restrict__ V, const int* __restrict__ EL,
            const float* __restrict__ MV, float* __restrict__ O,
            int* __restrict__ ticket) {
    const int t = threadIdx.x;
    {
        const int bh0    = blockIdx.x & (NBH - 1);
        const int qbase0 = (blockIdx.x >> 6) * 128;
        const int elb    = EL[bh0 >> 4];
        if (qbase0 >= elb) {
            float* Op = O + (size_t)bh0 * SQ * DH;
            const int c16 = t & 15, r0 = t >> 4;
            f32x4 mv = *(const f32x4*)(MV + bh0 * DH + c16 * 4);
            #pragma unroll
            for (int i = 0; i < 8; ++i)
                *(f32x4*)(Op + (size_t)(qbase0 + r0 + i * 16) * DH + c16 * 4) = mv;
        }
    }

    const int el0 = EL[0], el1 = EL[1], el2 = EL[2], el3 = EL[3];
    const int v0 = (el0 + 127) >> 7, v1 = (el1 + 127) >> 7;
    const int v2 = (el2 + 127) >> 7, v3 = (el3 + 127) >> 7;
    const int n0 = 16 * v0, n1 = n0 + 16 * v1, n2 = n1 + 16 * v2;
    const int nvalid = n2 + 16 * v3;

    __shared__ short Kb[TK][LDE];
    __shared__ short Vt[DH][LDE];
    __shared__ short Pl[4][32][LDE];
    __shared__ int item_s;

    const int wq = t >> 6, lane = t & 63, qd = lane >> 4, c = lane & 15;
    const int ksrow = t >> 2;
    const int ksdc  = t & 3;
    const int vpair = t & 31;
    const int vdg   = t >> 5;

    for (;;) {
        if (t == 0) item_s = atomicAdd(ticket, 1);
        __syncthreads();
        const int it = item_s;
        if (it >= nvalid) break;

        int b, u, vb, el;
        if      (it < n0) { b = 0; u = it;      vb = v0; el = el0; }
        else if (it < n1) { b = 1; u = it - n0; vb = v1; el = el1; }
        else if (it < n2) { b = 2; u = it - n1; vb = v2; el = el2; }
        else              { b = 3; u = it - n2; vb = v3; el = el3; }
        const int head  = u / vb;
        const int qt    = u - head * vb;
        const int bh    = b * 16 + head;
        const int qbase = qt * 128;

        const size_t base = (size_t)bh * SQ * DH;
        const float* Qp = Q + base;
        const float* Kp = K + base;
        const float* Vp = V + base;
        float* Op = O + base;

        const float sc = 0.125f * 1.44269504f;
        bf16x8 qf[2][2];
        #pragma unroll
        for (int nt = 0; nt < 2; ++nt) {
            const int row = qbase + wq * 32 + nt * 16 + c;
            #pragma unroll
            for (int kc = 0; kc < 2; ++kc) {
                const float* p = Qp + (size_t)row * DH + kc * 32 + qd * 8;
                f32x4 a  = *(const f32x4*)p;
                f32x4 bb = *(const f32x4*)(p + 4);
                u32x4 f;
                f[0] = pk2(a[0] * sc, a[1] * sc);
                f[1] = pk2(a[2] * sc, a[3] * sc);
                f[2] = pk2(bb[0] * sc, bb[1] * sc);
                f[3] = pk2(bb[2] * sc, bb[3] * sc);
                qf[nt][kc] = *(bf16x8*)&f;
            }
        }

        float l_[2] = {0.f, 0.f};
        f32x4 oacc[4][2];
        #pragma unroll
        for (int dt = 0; dt < 4; ++dt)
            #pragma unroll
            for (int nt = 0; nt < 2; ++nt)
                oacc[dt][nt] = (f32x4){0.f, 0.f, 0.f, 0.f};

        const int nkt = (el + TK - 1) / TK;

        f32x4 kg0, kg1, kg2, kg3, vg0, vg1, vg2, vg3;
        {
            const float* kp = Kp + (size_t)ksrow * DH + ksdc * 16;
            kg0 = *(const f32x4*)kp;
            kg1 = *(const f32x4*)(kp + 4);
            kg2 = *(const f32x4*)(kp + 8);
            kg3 = *(const f32x4*)(kp + 12);
            const float* vp0 = Vp + (size_t)(2 * vpair) * DH + vdg * 8;
            vg0 = *(const f32x4*)vp0;
            vg1 = *(const f32x4*)(vp0 + 4);
            vg2 = *(const f32x4*)(vp0 + DH);
            vg3 = *(const f32x4*)(vp0 + DH + 4);
        }

        for (int kt = 0; kt < nkt; ++kt) {
            const int k0 = kt * TK;

            __syncthreads();
            {
                u32x4 w0, w1;
                w0[0] = pk2(kg0[0], kg0[1]); w0[1] = pk2(kg0[2], kg0[3]);
                w0[2] = pk2(kg1[0], kg1[1]); w0[3] = pk2(kg1[2], kg1[3]);
                w1[0] = pk2(kg2[0], kg2[1]); w1[1] = pk2(kg2[2], kg2[3]);
                w1[2] = pk2(kg3[0], kg3[1]); w1[3] = pk2(kg3[2], kg3[3]);
                *(u32x4*)&Kb[ksrow][ksdc * 16]     = w0;
                *(u32x4*)&Kb[ksrow][ksdc * 16 + 8] = w1;
            }
            {
                #pragma unroll
                for (int i = 0; i < 4; ++i) {
                    *(unsigned int*)&Vt[vdg * 8 + i][2 * vpair]     = pk2(vg0[i], vg2[i]);
                    *(unsigned int*)&Vt[vdg * 8 + 4 + i][2 * vpair] = pk2(vg1[i], vg3[i]);
                }
            }
            __syncthreads();

            if (kt + 1 < nkt) {
                const int kn = k0 + TK;
                const float* kp = Kp + (size_t)(kn + ksrow) * DH + ksdc * 16;
                kg0 = *(const f32x4*)kp;
                kg1 = *(const f32x4*)(kp + 4);
                kg2 = *(const f32x4*)(kp + 8);
                kg3 = *(const f32x4*)(kp + 12);
                const float* vp0 = Vp + (size_t)(kn + 2 * vpair) * DH + vdg * 8;
                vg0 = *(const f32x4*)vp0;
                vg1 = *(const f32x4*)(vp0 + 4);
                vg2 = *(const f32x4*)(vp0 + DH);
                vg3 = *(const f32x4*)(vp0 + DH + 4);
            }

            f32x4 st[4][2];
            #pragma unroll
            for (int mt = 0; mt < 4; ++mt) {
                bf16x8 a0 = *(const bf16x8*)&Kb[mt * 16 + c][qd * 8];
                bf16x8 a1 = *(const bf16x8*)&Kb[mt * 16 + c][32 + qd * 8];
                #pragma unroll
                for (int nt = 0; nt < 2; ++nt) {
                    f32x4 acc = (f32x4){0.f, 0.f, 0.f, 0.f};
                    acc = __builtin_amdgcn_mfma_f32_16x16x32_bf16(a0, qf[nt][0], acc, 0, 0, 0);
                    acc = __builtin_amdgcn_mfma_f32_16x16x32_bf16(a1, qf[nt][1], acc, 0, 0, 0);
                    st[mt][nt] = acc;
                }
            }

            if (k0 + TK > el) {
                #pragma unroll
                for (int mt = 0; mt < 4; ++mt)
                    #pragma unroll
                    for (int r = 0; r < 4; ++r)
                        if (k0 + mt * 16 + qd * 4 + r >= el) {
                            st[mt][0][r] = -1e30f;
                            st[mt][1][r] = -1e30f;
                        }
            }

            #pragma unroll
            for (int nt = 0; nt < 2; ++nt) {
                #pragma unroll
                for (int mt = 0; mt < 4; ++mt) {
                    const float p0 = exp2f(st[mt][nt][0]);
                    const float p1 = exp2f(st[mt][nt][1]);
                    const float p2 = exp2f(st[mt][nt][2]);
                    const float p3 = exp2f(st[mt][nt][3]);
                    l_[nt] += (p0 + p1) + (p2 + p3);
                    u32x2 pw;
                    pw[0] = pk2(p0, p1);
                    pw[1] = pk2(p2, p3);
                    *(u32x2*)&Pl[wq][nt * 16 + c][mt * 16 + qd * 4] = pw;
                }
            }

            #pragma unroll
            for (int kc = 0; kc < 2; ++kc) {
                bf16x8 pb0 = *(const bf16x8*)&Pl[wq][c][kc * 32 + qd * 8];
                bf16x8 pb1 = *(const bf16x8*)&Pl[wq][16 + c][kc * 32 + qd * 8];
                #pragma unroll
                for (int dt = 0; dt < 4; ++dt) {
                    bf16x8 vf = *(const bf16x8*)&Vt[dt * 16 + c][kc * 32 + qd * 8];
                    oacc[dt][0] = __builtin_amdgcn_mfma_f32_16x16x32_bf16(vf, pb0, oacc[dt][0], 0, 0, 0);
                    oacc[dt][1] = __builtin_amdgcn_mfma_f32_16x16x32_bf16(vf, pb1, oacc[dt][1], 0, 0, 0);
                }
            }
        }

        #pragma unroll
        for (int nt = 0; nt < 2; ++nt) {
            l_[nt] += __shfl_xor(l_[nt], 16);
            l_[nt] += __shfl_xor(l_[nt], 32);
        }

        #pragma unroll
        for (int nt = 0; nt < 2; ++nt) {
            const int row = qbase + wq * 32 + nt * 16 + c;
            if (row < el) {
                const float inv = 1.0f / l_[nt];
                #pragma unroll
                for (int dt = 0; dt < 4; ++dt) {
                    f32x4 o = oacc[dt][nt];
                    o[0] *= inv; o[1] *= inv; o[2] *= inv; o[3] *= inv;
                    *(f32x4*)(Op + (size_t)row * DH + dt * 16 + qd * 4) = o;
                }
            } else {
                #pragma unroll
                for (int dt = 0; dt < 4; ++dt) {
                    f32x4 mv = *(const f32x4*)(MV + bh * DH + dt * 16 + qd * 4);
                    *(f32x4*)(Op + (size_t)row * DH + dt * 16 + qd * 4) = mv;
                }
            }
        }
    }
}

// ============================================================================

extern "C" void kernel_launch(void* const* d_in, const int* in_sizes, int n_in,
                              void* d_out, int out_size, void* d_ws, size_t ws_size,
                              hipStream_t stream) {
    const float* q  = (const float*)d_in[0];
    const float* k  = (const float*)d_in[1];
    const float* v  = (const float*)d_in[2];
    const int*   el = (const int*)d_in[3];
    float* out = (float*)d_out;

    const size_t kbt_bytes = (size_t)NBH * NTILE * TILE_B;      // 16 MiB
    const size_t needed    = 65536 + 2 * kbt_bytes;             // ~33.6 MiB

    if (ws_size >= needed) {
        // new path: fragment-ordered prepass + non-draining-barrier flash
        float* mv  = (float*)d_ws;
        int*   tk  = (int*)((char*)d_ws + 16384);               // 8 group tickets
        char*  kbt = (char*)d_ws + 65536;
        char*  vbt = kbt + kbt_bytes;

        hipMemsetAsync(d_ws, 0, 65536, stream);
        convkv<<<dim3(NBH * NTILE), dim3(256), 0, stream>>>(k, v, el, mv, kbt, vbt);
        flash13<<<dim3(NBH * (SQ / 256)), dim3(512), 0, stream>>>(q, el, mv, out, kbt, vbt, tk);
    } else {
        // fallback: proven R5 path
        float* mv = (float*)d_ws;
        int*   tk = (int*)((char*)d_ws + NBH * DH * sizeof(float));

        hipMemsetAsync(d_ws, 0, NBH * DH * sizeof(float) + 64, stream);
        meanv_k<<<dim3(NBH * 16), dim3(256), 0, stream>>>(v, mv);
        flash5<<<dim3(NBH * (SQ / 128)), dim3(256), 0, stream>>>(q, k, v, el, mv, out, tk);
    }
}

// Round 9
// 190.214 us; speedup vs baseline: 1.1715x; 1.0122x over previous
//
#include <hip/hip_runtime.h>
#include <hip/hip_bf16.h>

// InnocentAttention: B=4 H=16 S=2048 D=64, fp32 in/out, per-batch event_length mask.
//
// R14: decorrelate the dependency chains. R13 proved the plateau is not drain
// (raw barrier + counted vmcnt == __syncthreads, 73us both) -- counters show
// ~1 working 8-wave block per CU, barrier-lockstepped into ONE chain at
// 2 waves/SIMD. Fix: 64-q items, 2-wave/128-thread blocks, 2-slot ring
// (32KB LDS -> 4 blocks/CU): ~4 INDEPENDENT chains per CU; one block's
// LDS/MFMA stalls are filled by another block's issue. Everything else kept:
// fragment-ordered workspace, XCD-affinity queues, raw barriers, counted
// vmcnt, largest-batch-first decode.
// Falls back to the proven R5 path when ws_size < ~33.6 MB.

#define SQ 2048
#define DH 64
#define NBH 64
#define TK 64
#define NTILE 32           // SQ / TK
#define TILE_B 8192        // TK * DH * 2 bytes (bf16)
#define LDE 72             // fallback-path padded LDS stride
#define LVP 68             // prepass V-stage stride

typedef __attribute__((ext_vector_type(4))) float f32x4;
typedef __attribute__((ext_vector_type(8))) short bf16x8;
typedef __attribute__((ext_vector_type(4))) unsigned int u32x4;
typedef __attribute__((ext_vector_type(2))) unsigned int u32x2;

#define VMCNT(n) asm volatile("s_waitcnt vmcnt(" #n ")" ::: "memory")
#define RAW_BARRIER() asm volatile("s_barrier" ::: "memory")

__device__ __forceinline__ unsigned int pk2(float lo, float hi) {
    // v_cvt_pk_bf16_f32 on gfx950 (RNE), lo -> low 16 bits
    __hip_bfloat162 h = __float22bfloat162_rn(float2{lo, hi});
    union { __hip_bfloat162 h; unsigned int u; } c; c.h = h;
    return c.u;
}

__device__ __forceinline__ float bfu16_to_f(unsigned short s) {
    union { unsigned int u; float f; } c; c.u = ((unsigned int)s) << 16;
    return c.f;
}

__device__ __forceinline__ void async_cp16(const void* g, void* l) {
    // global -> LDS direct DMA, 16B/lane; LDS dest = wave-uniform base + lane*16
    __builtin_amdgcn_global_load_lds(
        (const __attribute__((address_space(1))) unsigned int*)g,
        (__attribute__((address_space(3))) unsigned int*)l, 16, 0, 0);
}

// ============================================================================
// NEW PATH
// ============================================================================

// Prepass (validated R8-R13): one block per (bh, 64-key tile). Fragment-ordered:
//  K tile: line fi = mt*2+half (1KB); lane l=(qd*16+c): 16B =
//          K[key=mt*16+c][d = half*32+qd*8 .. +7] bf16.
//  V tile: line fi = kc*4+dt; lane l: element j =
//          V[key = kc*32 + (j>>2)*16 + qd*4 + (j&3)][d = dt*16+c]  (pi order)
//  MV[bh][d] += mean contribution of this tile's 64 V rows (atomic)
__global__ __launch_bounds__(256)
void convkv(const float* __restrict__ K, const float* __restrict__ V,
            const int* __restrict__ EL, float* __restrict__ MV,
            char* __restrict__ Kbt, char* __restrict__ Vbt) {
    const int bh = blockIdx.x >> 5;
    const int kt = blockIdx.x & 31;
    const int k0 = kt * TK;
    const int el = EL[bh >> 4];
    const int t = threadIdx.x;
    const int r  = t >> 2;      // key row 0..63
    const int dc = t & 3;       // 16-d chunk

    __shared__ short LV[64][LVP];

    // stage V row (bf16) into LDS for transpose + mean
    {
        const float* vp = V + ((size_t)bh * SQ + k0 + r) * DH + dc * 16;
        f32x4 a = *(const f32x4*)vp;
        f32x4 b = *(const f32x4*)(vp + 4);
        f32x4 c2 = *(const f32x4*)(vp + 8);
        f32x4 d2 = *(const f32x4*)(vp + 12);
        u32x4 w0, w1;
        w0[0] = pk2(a[0], a[1]);  w0[1] = pk2(a[2], a[3]);
        w0[2] = pk2(b[0], b[1]);  w0[3] = pk2(b[2], b[3]);
        w1[0] = pk2(c2[0], c2[1]); w1[1] = pk2(c2[2], c2[3]);
        w1[2] = pk2(d2[0], d2[1]); w1[3] = pk2(d2[2], d2[3]);
        *(u32x4*)&LV[r][dc * 16]     = w0;
        *(u32x4*)&LV[r][dc * 16 + 8] = w1;
    }

    // K convert (valid tiles only) -> fragment-ordered lines
    if (k0 < el) {
        const float* kp = K + ((size_t)bh * SQ + k0 + r) * DH + dc * 16;
        f32x4 a = *(const f32x4*)kp;
        f32x4 b = *(const f32x4*)(kp + 4);
        f32x4 c2 = *(const f32x4*)(kp + 8);
        f32x4 d2 = *(const f32x4*)(kp + 12);
        u32x4 w0, w1;
        w0[0] = pk2(a[0], a[1]);  w0[1] = pk2(a[2], a[3]);
        w0[2] = pk2(b[0], b[1]);  w0[3] = pk2(b[2], b[3]);
        w1[0] = pk2(c2[0], c2[1]); w1[1] = pk2(c2[2], c2[3]);
        w1[2] = pk2(d2[0], d2[1]); w1[3] = pk2(d2[2], d2[3]);
        char* kb = Kbt + (size_t)(bh * NTILE + kt) * TILE_B;
        const int fi  = (r >> 4) * 2 + (dc >> 1);
        const int qd0 = (dc & 1) * 2;
        char* d0 = kb + fi * 1024 + qd0 * 256 + (r & 15) * 16;
        *(u32x4*)d0         = w0;
        *(u32x4*)(d0 + 256) = w1;
    }

    __syncthreads();

    // transpose-read V in pi order + mean partial
    const int dd  = t >> 2;     // d row 0..63
    const int seg = t & 3;      // 16-pos segment
    float msum = 0.f;
    unsigned int wv[8];
    #pragma unroll
    for (int i = 0; i < 8; ++i) {
        const int pos = seg * 16 + 2 * i;
        const int key = (pos & ~31) | ((pos & 4) << 2) | ((pos & 24) >> 1) | (pos & 3);
        const unsigned short s0 = (unsigned short)LV[key][dd];
        const unsigned short s1 = (unsigned short)LV[key + 1][dd];
        msum += bfu16_to_f(s0) + bfu16_to_f(s1);
        wv[i] = (unsigned int)s0 | ((unsigned int)s1 << 16);
    }
    msum += __shfl_xor(msum, 1);
    msum += __shfl_xor(msum, 2);
    if (seg == 0) atomicAdd(&MV[bh * DH + dd], msum * (1.0f / (float)SQ));

    if (k0 < el) {
        char* vbb = Vbt + (size_t)(bh * NTILE + kt) * TILE_B;
        const int fi  = (seg >> 1) * 4 + (dd >> 4);
        const int qd0 = (seg & 1) * 2;
        char* d0 = vbb + fi * 1024 + qd0 * 256 + (dd & 15) * 16;
        u32x4 o0 = {wv[0], wv[1], wv[2], wv[3]};
        u32x4 o1 = {wv[4], wv[5], wv[6], wv[7]};
        *(u32x4*)d0         = o0;
        *(u32x4*)(d0 + 256) = o1;
    }
}

// Main kernel: 128 threads = 2 waves, each wave owns 32 queries of a 64-q item.
// 2-slot ring, raw barriers (2-wave, cheap), counted vmcnt, per-XCD queues.
__global__ __launch_bounds__(128, 2)
void flash14(const float* __restrict__ Q, const int* __restrict__ EL,
             const float* __restrict__ MV, float* __restrict__ O,
             const char* __restrict__ Kbt, const char* __restrict__ Vbt,
             int* __restrict__ ticket) {
    const int t = threadIdx.x;

    // ---------- static phase: mean(V) rows above ceil64(el) -----------------
    {
        const int bh0 = blockIdx.x & (NBH - 1);
        const int qb0 = (blockIdx.x >> 6) * 128;     // grid 1024: 16 chunks x 128q
        const int el64b = (EL[bh0 >> 4] + 63) & ~63;
        if (qb0 + 127 >= el64b) {
            float* Op = O + (size_t)bh0 * SQ * DH;
            const int c16 = t & 15, r0 = t >> 4;     // r0 0..7
            f32x4 mv = *(const f32x4*)(MV + bh0 * DH + c16 * 4);
            #pragma unroll
            for (int i = 0; i < 16; ++i) {
                const int row = qb0 + r0 + i * 8;
                if (row >= el64b)
                    *(f32x4*)(Op + (size_t)row * DH + c16 * 4) = mv;
            }
        }
    }

    // ---------- batch table, sorted descending by el (register network) ------
    int ka0 = EL[0], va0 = 0;
    int ka1 = EL[1], va1 = 1;
    int ka2 = EL[2], va2 = 2;
    int ka3 = EL[3], va3 = 3;
    #define CSWAP(x, y) if (ka##x < ka##y) { int tk_ = ka##x, tv_ = va##x; \
        ka##x = ka##y; va##x = va##y; ka##y = tk_; va##y = tv_; }
    CSWAP(0, 1) CSWAP(2, 3) CSWAP(0, 2) CSWAP(1, 3) CSWAP(1, 2)
    #undef CSWAP
    const int c0 = 2 * ((ka0 + 63) >> 6);    // items per (group, batch): 2 heads x qtiles
    const int c1 = 2 * ((ka1 + 63) >> 6);
    const int c2 = 2 * ((ka2 + 63) >> 6);
    const int c3 = 2 * ((ka3 + 63) >> 6);
    const int nvalid = c0 + c1 + c2 + c3;    // identical for every group

    __shared__ char KB[2 * TILE_B];
    __shared__ char VB[2 * TILE_B];
    __shared__ int item_s;

    const int grp = blockIdx.x & 7;          // blockIdx%8 ~ XCD (perf-only assumption)
    const int wq = t >> 6, lane = t & 63, qd = lane >> 4, c = lane & 15;
    const float sc = 0.125f * 1.44269504f;   // 1/sqrt(D) * log2(e)

    for (;;) {
        if (t == 0) item_s = atomicAdd(&ticket[grp], 1);
        __syncthreads();                     // item boundary (full drain is fine)
        const int it = item_s;
        if (it >= nvalid) break;

        // decode (largest batch first)
        int u = it, b, el;
        if (u < c0)             { b = va0; el = ka0; }
        else { u -= c0;
        if (u < c1)             { b = va1; el = ka1; }
        else { u -= c1;
        if (u < c2)             { b = va2; el = ka2; }
        else { u -= c2;           b = va3; el = ka3; } } }
        const int vb_ = (el + 63) >> 6;
        const int hh  = u / vb_;
        const int qt  = u - hh * vb_;
        const int bh  = b * 16 + grp + hh * 8;   // head%8 == grp -> L2 affinity
        const int qbase = qt * 64;

        const float* Qp = Q + (size_t)bh * SQ * DH;
        float*       Op = O + (size_t)bh * SQ * DH;
        // staging: 128 threads x 16B x 4 rounds cover one 8KB tile
        const char*  Kt = Kbt + (size_t)bh * NTILE * TILE_B + t * 16;
        const char*  Vt = Vbt + (size_t)bh * NTILE * TILE_B + t * 16;

        const int nkt = (el + TK - 1) >> 6;

        #define STAGE(kt_, s_) {                                               \
            const char* gk_ = Kt + (size_t)(kt_) * TILE_B;                     \
            const char* gv_ = Vt + (size_t)(kt_) * TILE_B;                     \
            char* lk_ = KB + (s_) * TILE_B + t * 16;                           \
            char* lv_ = VB + (s_) * TILE_B + t * 16;                           \
            _Pragma("unroll")                                                  \
            for (int j_ = 0; j_ < 4; ++j_)                                     \
                async_cp16(gk_ + j_ * 2048, lk_ + j_ * 2048);                  \
            _Pragma("unroll")                                                  \
            for (int j_ = 0; j_ < 4; ++j_)                                     \
                async_cp16(gv_ + j_ * 2048, lv_ + j_ * 2048);                  \
        }

        // prologue: tile 0 in flight (8 VMEM instr)
        STAGE(0, 0)

        // Q fragments (B-operand of S^T = K*Q^T); scale folded in
        const int qrow0 = qbase + wq * 32;
        bf16x8 qf[2][2];
        #pragma unroll
        for (int nt = 0; nt < 2; ++nt) {
            const int row = qrow0 + nt * 16 + c;
            #pragma unroll
            for (int kc = 0; kc < 2; ++kc) {
                const float* p = Qp + (size_t)row * DH + kc * 32 + qd * 8;
                f32x4 a  = *(const f32x4*)p;
                f32x4 bq = *(const f32x4*)(p + 4);
                u32x4 f;
                f[0] = pk2(a[0] * sc, a[1] * sc);
                f[1] = pk2(a[2] * sc, a[3] * sc);
                f[2] = pk2(bq[0] * sc, bq[1] * sc);
                f[3] = pk2(bq[2] * sc, bq[3] * sc);
                qf[nt][kc] = *(bf16x8*)&f;
            }
        }

        float l_[2] = {0.f, 0.f};
        f32x4 oacc[4][2];
        #pragma unroll
        for (int dt = 0; dt < 4; ++dt) {
            oacc[dt][0] = (f32x4){0.f, 0.f, 0.f, 0.f};
            oacc[dt][1] = (f32x4){0.f, 0.f, 0.f, 0.f};
        }

        for (int kt = 0; kt < nkt; ++kt) {
            const int s = kt & 1;

            // both waves done computing tile kt-1 -> slot s^1 reusable.
            RAW_BARRIER();
            if (kt + 1 < nkt) STAGE(kt + 1, s ^ 1)
            // counted wait: own tile-kt copies done; next tile stays in flight
            if (kt + 1 < nkt) VMCNT(8); else VMCNT(0);
            RAW_BARRIER();                   // both waves' tile-kt lines visible

            const char* Kb = KB + s * TILE_B + lane * 16;
            const char* Vb = VB + s * TILE_B + lane * 16;

            // ---- S^T = K * Q^T : contiguous fragment-line reads ----
            f32x4 st[4][2];
            __builtin_amdgcn_s_setprio(1);
            #pragma unroll
            for (int mt = 0; mt < 4; ++mt) {
                bf16x8 a0 = *(const bf16x8*)(Kb + (mt * 2) * 1024);
                bf16x8 a1 = *(const bf16x8*)(Kb + (mt * 2 + 1) * 1024);
                #pragma unroll
                for (int nt = 0; nt < 2; ++nt) {
                    f32x4 acc = (f32x4){0.f, 0.f, 0.f, 0.f};
                    acc = __builtin_amdgcn_mfma_f32_16x16x32_bf16(a0, qf[nt][0], acc, 0, 0, 0);
                    acc = __builtin_amdgcn_mfma_f32_16x16x32_bf16(a1, qf[nt][1], acc, 0, 0, 0);
                    st[mt][nt] = acc;
                }
            }
            __builtin_amdgcn_s_setprio(0);

            const int k0 = kt * TK;
            if (k0 + TK > el) {    // straddling tile: mask invalid keys
                #pragma unroll
                for (int mt = 0; mt < 4; ++mt)
                    #pragma unroll
                    for (int r = 0; r < 4; ++r)
                        if (k0 + mt * 16 + qd * 4 + r >= el) {
                            st[mt][0][r] = -1e30f;
                            st[mt][1][r] = -1e30f;
                        }
            }

            // ---- p = exp2(s); pack in-register (pi order == lane's own keys) ----
            u32x4 pw[2][2];
            #pragma unroll
            for (int nt = 0; nt < 2; ++nt) {
                #pragma unroll
                for (int mt = 0; mt < 4; ++mt) {
                    const float p0 = __builtin_amdgcn_exp2f(st[mt][nt][0]);
                    const float p1 = __builtin_amdgcn_exp2f(st[mt][nt][1]);
                    const float p2 = __builtin_amdgcn_exp2f(st[mt][nt][2]);
                    const float p3 = __builtin_amdgcn_exp2f(st[mt][nt][3]);
                    l_[nt] += (p0 + p1) + (p2 + p3);
                    pw[nt][mt >> 1][(mt & 1) * 2]     = pk2(p0, p1);
                    pw[nt][mt >> 1][(mt & 1) * 2 + 1] = pk2(p2, p3);
                }
            }

            // ---- O^T += V^T * P^T : V lines pi-permuted, P in-register ----
            __builtin_amdgcn_s_setprio(1);
            #pragma unroll
            for (int kc = 0; kc < 2; ++kc) {
                bf16x8 pb0 = *(bf16x8*)&pw[0][kc];
                bf16x8 pb1 = *(bf16x8*)&pw[1][kc];
                #pragma unroll
                for (int dt = 0; dt < 4; ++dt) {
                    bf16x8 vf = *(const bf16x8*)(Vb + (kc * 4 + dt) * 1024);
                    oacc[dt][0] = __builtin_amdgcn_mfma_f32_16x16x32_bf16(vf, pb0, oacc[dt][0], 0, 0, 0);
                    oacc[dt][1] = __builtin_amdgcn_mfma_f32_16x16x32_bf16(vf, pb1, oacc[dt][1], 0, 0, 0);
                }
            }
            __builtin_amdgcn_s_setprio(0);
        }
        #undef STAGE

        // denominators: cross-lane combine over qd groups (same query col c)
        #pragma unroll
        for (int nt = 0; nt < 2; ++nt) {
            l_[nt] += __shfl_xor(l_[nt], 16);
            l_[nt] += __shfl_xor(l_[nt], 32);
        }

        #pragma unroll
        for (int nt = 0; nt < 2; ++nt) {
            const int qrow = qrow0 + nt * 16 + c;
            if (qrow < el) {
                const float inv = 1.0f / l_[nt];
                #pragma unroll
                for (int dt = 0; dt < 4; ++dt) {
                    f32x4 o = oacc[dt][nt];
                    o[0] *= inv; o[1] *= inv; o[2] *= inv; o[3] *= inv;
                    *(f32x4*)(Op + (size_t)qrow * DH + dt * 16 + qd * 4) = o;
                }
            } else {
                #pragma unroll
                for (int dt = 0; dt < 4; ++dt)
                    *(f32x4*)(Op + (size_t)qrow * DH + dt * 16 + qd * 4) =
                        *(const f32x4*)(MV + bh * DH + dt * 16 + qd * 4);
            }
        }
    }
}

// ============================================================================
// FALLBACK PATH (proven R5 kernels, used when ws_size < ~33.6 MB)
// ============================================================================

__global__ __launch_bounds__(256)
void meanv_k(const float* __restrict__ V, float* __restrict__ MV) {
    const int bh  = blockIdx.x >> 4;
    const int seg = blockIdx.x & 15;
    const float* vp = V + ((size_t)bh * SQ + (size_t)seg * 128) * DH;
    const int c = threadIdx.x & 15;
    const int r = threadIdx.x >> 4;
    const float* p = vp + (size_t)r * DH + c * 4;
    f32x4 s0 = *(const f32x4*)(p);
    f32x4 s1 = *(const f32x4*)(p + 16 * DH);
    f32x4 s2 = *(const f32x4*)(p + 32 * DH);
    f32x4 s3 = *(const f32x4*)(p + 48 * DH);
    s0 += *(const f32x4*)(p + 64 * DH);
    s1 += *(const f32x4*)(p + 80 * DH);
    s2 += *(const f32x4*)(p + 96 * DH);
    s3 += *(const f32x4*)(p + 112 * DH);
    f32x4 s = (s0 + s1) + (s2 + s3);
    __shared__ f32x4 red[16][16];
    red[r][c] = s;
    __syncthreads();
    if (threadIdx.x < 16) {
        f32x4 a = red[0][threadIdx.x];
        #pragma unroll
        for (int j = 1; j < 16; ++j) a += red[j][threadIdx.x];
        const float inv = 1.0f / (float)SQ;
        atomicAdd(&MV[bh * DH + threadIdx.x * 4 + 0], a[0] * inv);
        atomicAdd(&MV[bh * DH + threadIdx.x * 4 + 1], a[1] * inv);
        atomicAdd(&MV[bh * DH + threadIdx.x * 4 + 2], a[2] * inv);
        atomicAdd(&MV[bh * DH + threadIdx.x * 4 + 3], a[3] * inv);
    }
}

__global__ __launch_bounds__(256, 3)
void flash5(const float* __restrict__ Q, const float* __restrict__ K,
            const float* __restrict__ V, const int* __restrict__ EL,
            const float* __restrict__ MV, float* __restrict__ O,
            int* __restrict__ ticket) {
    const int t = threadIdx.x;
    {
        const int bh0    = blockIdx.x & (NBH - 1);
        const int qbase0 = (blockIdx.x >> 6) * 128;
        const int elb    = EL[bh0 >> 4];
        if (qbase0 >= elb) {
            float* Op = O + (size_t)bh0 * SQ * DH;
            const int c16 = t & 15, r0 = t >> 4;
            f32x4 mv = *(const f32x4*)(MV + bh0 * DH + c16 * 4);
            #pragma unroll
            for (int i = 0; i < 8; ++i)
                *(f32x4*)(Op + (size_t)(qbase0 + r0 + i * 16) * DH + c16 * 4) = mv;
        }
    }

    const int el0 = EL[0], el1 = EL[1], el2 = EL[2], el3 = EL[3];
    const int v0 = (el0 + 127) >> 7, v1 = (el1 + 127) >> 7;
    const int v2 = (el2 + 127) >> 7, v3 = (el3 + 127) >> 7;
    const int n0 = 16 * v0, n1 = n0 + 16 * v1, n2 = n1 + 16 * v2;
    const int nvalid = n2 + 16 * v3;

    __shared__ short Kb[TK][LDE];
    __shared__ short Vt[DH][LDE];
    __shared__ short Pl[4][32][LDE];
    __shared__ int item_s;

    const int wq = t >> 6, lane = t & 63, qd = lane >> 4, c = lane & 15;
    const int ksrow = t >> 2;
    const int ksdc  = t & 3;
    const int vpair = t & 31;
    const int vdg   = t >> 5;

    for (;;) {
        if (t == 0) item_s = atomicAdd(ticket, 1);
        __syncthreads();
        const int it = item_s;
        if (it >= nvalid) break;

        int b, u, vb, el;
        if      (it < n0) { b = 0; u = it;      vb = v0; el = el0; }
        else if (it < n1) { b = 1; u = it - n0; vb = v1; el = el1; }
        else if (it < n2) { b = 2; u = it - n1; vb = v2; el = el2; }
        else              { b = 3; u = it - n2; vb = v3; el = el3; }
        const int head  = u / vb;
        const int qt    = u - head * vb;
        const int bh    = b * 16 + head;
        const int qbase = qt * 128;

        const size_t base = (size_t)bh * SQ * DH;
        const float* Qp = Q + base;
        const float* Kp = K + base;
        const float* Vp = V + base;
        float* Op = O + base;

        const float sc = 0.125f * 1.44269504f;
        bf16x8 qf[2][2];
        #pragma unroll
        for (int nt = 0; nt < 2; ++nt) {
            const int row = qbase + wq * 32 + nt * 16 + c;
            #pragma unroll
            for (int kc = 0; kc < 2; ++kc) {
                const float* p = Qp + (size_t)row * DH + kc * 32 + qd * 8;
                f32x4 a  = *(const f32x4*)p;
                f32x4 bb = *(const f32x4*)(p + 4);
                u32x4 f;
                f[0] = pk2(a[0] * sc, a[1] * sc);
                f[1] = pk2(a[2] * sc, a[3] * sc);
                f[2] = pk2(bb[0] * sc, bb[1] * sc);
                f[3] = pk2(bb[2] * sc, bb[3] * sc);
                qf[nt][kc] = *(bf16x8*)&f;
            }
        }

        float l_[2] = {0.f, 0.f};
        f32x4 oacc[4][2];
        #pragma unroll
        for (int dt = 0; dt < 4; ++dt)
            #pragma unroll
            for (int nt = 0; nt < 2; ++nt)
                oacc[dt][nt] = (f32x4){0.f, 0.f, 0.f, 0.f};

        const int nkt = (el + TK - 1) / TK;

        f32x4 kg0, kg1, kg2, kg3, vg0, vg1, vg2, vg3;
        {
            const float* kp = Kp + (size_t)ksrow * DH + ksdc * 16;
            kg0 = *(const f32x4*)kp;
            kg1 = *(const f32x4*)(kp + 4);
            kg2 = *(const f32x4*)(kp + 8);
            kg3 = *(const f32x4*)(kp + 12);
            const float* vp0 = Vp + (size_t)(2 * vpair) * DH + vdg * 8;
            vg0 = *(const f32x4*)vp0;
            vg1 = *(const f32x4*)(vp0 + 4);
            vg2 = *(const f32x4*)(vp0 + DH);
            vg3 = *(const f32x4*)(vp0 + DH + 4);
        }

        for (int kt = 0; kt < nkt; ++kt) {
            const int k0 = kt * TK;

            __syncthreads();
            {
                u32x4 w0, w1;
                w0[0] = pk2(kg0[0], kg0[1]); w0[1] = pk2(kg0[2], kg0[3]);
                w0[2] = pk2(kg1[0], kg1[1]); w0[3] = pk2(kg1[2], kg1[3]);
                w1[0] = pk2(kg2[0], kg2[1]); w1[1] = pk2(kg2[2], kg2[3]);
                w1[2] = pk2(kg3[0], kg3[1]); w1[3] = pk2(kg3[2], kg3[3]);
                *(u32x4*)&Kb[ksrow][ksdc * 16]     = w0;
                *(u32x4*)&Kb[ksrow][ksdc * 16 + 8] = w1;
            }
            {
                #pragma unroll
                for (int i = 0; i < 4; ++i) {
                    *(unsigned int*)&Vt[vdg * 8 + i][2 * vpair]     = pk2(vg0[i], vg2[i]);
                    *(unsigned int*)&Vt[vdg * 8 + 4 + i][2 * vpair] = pk2(vg1[i], vg3[i]);
                }
            }
            __syncthreads();

            if (kt + 1 < nkt) {
                const int kn = k0 + TK;
                const float* kp = Kp + (size_t)(kn + ksrow) * DH + ksdc * 16;
                kg0 = *(const f32x4*)kp;
                kg1 = *(const f32x4*)(kp + 4);
                kg2 = *(const f32x4*)(kp + 8);
                kg3 = *(const f32x4*)(kp + 12);
                const float* vp0 = Vp + (size_t)(kn + 2 * vpair) * DH + vdg * 8;
                vg0 = *(const f32x4*)vp0;
                vg1 = *(const f32x4*)(vp0 + 4);
                vg2 = *(const f32x4*)(vp0 + DH);
                vg3 = *(const f32x4*)(vp0 + DH + 4);
            }

            f32x4 st[4][2];
            #pragma unroll
            for (int mt = 0; mt < 4; ++mt) {
                bf16x8 a0 = *(const bf16x8*)&Kb[mt * 16 + c][qd * 8];
                bf16x8 a1 = *(const bf16x8*)&Kb[mt * 16 + c][32 + qd * 8];
                #pragma unroll
                for (int nt = 0; nt < 2; ++nt) {
                    f32x4 acc = (f32x4){0.f, 0.f, 0.f, 0.f};
                    acc = __builtin_amdgcn_mfma_f32_16x16x32_bf16(a0, qf[nt][0], acc, 0, 0, 0);
                    acc = __builtin_amdgcn_mfma_f32_16x16x32_bf16(a1, qf[nt][1], acc, 0, 0, 0);
                    st[mt][nt] = acc;
                }
            }

            if (k0 + TK > el) {
                #pragma unroll
                for (int mt = 0; mt < 4; ++mt)
                    #pragma unroll
                    for (int r = 0; r < 4; ++r)
                        if (k0 + mt * 16 + qd * 4 + r >= el) {
                            st[mt][0][r] = -1e30f;
                            st[mt][1][r] = -1e30f;
                        }
            }

            #pragma unroll
            for (int nt = 0; nt < 2; ++nt) {
                #pragma unroll
                for (int mt = 0; mt < 4; ++mt) {
                    const float p0 = exp2f(st[mt][nt][0]);
                    const float p1 = exp2f(st[mt][nt][1]);
                    const float p2 = exp2f(st[mt][nt][2]);
                    const float p3 = exp2f(st[mt][nt][3]);
                    l_[nt] += (p0 + p1) + (p2 + p3);
                    u32x2 pw;
                    pw[0] = pk2(p0, p1);
                    pw[1] = pk2(p2, p3);
                    *(u32x2*)&Pl[wq][nt * 16 + c][mt * 16 + qd * 4] = pw;
                }
            }

            #pragma unroll
            for (int kc = 0; kc < 2; ++kc) {
                bf16x8 pb0 = *(const bf16x8*)&Pl[wq][c][kc * 32 + qd * 8];
                bf16x8 pb1 = *(const bf16x8*)&Pl[wq][16 + c][kc * 32 + qd * 8];
                #pragma unroll
                for (int dt = 0; dt < 4; ++dt) {
                    bf16x8 vf = *(const bf16x8*)&Vt[dt * 16 + c][kc * 32 + qd * 8];
                    oacc[dt][0] = __builtin_amdgcn_mfma_f32_16x16x32_bf16(vf, pb0, oacc[dt][0], 0, 0, 0);
                    oacc[dt][1] = __builtin_amdgcn_mfma_f32_16x16x32_bf16(vf, pb1, oacc[dt][1], 0, 0, 0);
                }
            }
        }

        #pragma unroll
        for (int nt = 0; nt < 2; ++nt) {
            l_[nt] += __shfl_xor(l_[nt], 16);
            l_[nt] += __shfl_xor(l_[nt], 32);
        }

        #pragma unroll
        for (int nt = 0; nt < 2; ++nt) {
            const int row = qbase + wq * 32 + nt * 16 + c;
            if (row < el) {
                const float inv = 1.0f / l_[nt];
                #pragma unroll
                for (int dt = 0; dt < 4; ++dt) {
                    f32x4 o = oacc[dt][nt];
                    o[0] *= inv; o[1] *= inv; o[2] *= inv; o[3] *= inv;
                    *(f32x4*)(Op + (size_t)row * DH + dt * 16 + qd * 4) = o;
                }
            } else {
                #pragma unroll
                for (int dt = 0; dt < 4; ++dt) {
                    f32x4 mv = *(const f32x4*)(MV + bh * DH + dt * 16 + qd * 4);
                    *(f32x4*)(Op + (size_t)row * DH + dt * 16 + qd * 4) = mv;
                }
            }
        }
    }
}

// ============================================================================

extern "C" void kernel_launch(void* const* d_in, const int* in_sizes, int n_in,
                              void* d_out, int out_size, void* d_ws, size_t ws_size,
                              hipStream_t stream) {
    const float* q  = (const float*)d_in[0];
    const float* k  = (const float*)d_in[1];
    const float* v  = (const float*)d_in[2];
    const int*   el = (const int*)d_in[3];
    float* out = (float*)d_out;

    const size_t kbt_bytes = (size_t)NBH * NTILE * TILE_B;      // 16 MiB
    const size_t needed    = 65536 + 2 * kbt_bytes;             // ~33.6 MiB

    if (ws_size >= needed) {
        // new path: fragment-ordered prepass + decorrelated 2-wave-block flash
        float* mv  = (float*)d_ws;
        int*   tk  = (int*)((char*)d_ws + 16384);               // 8 group tickets
        char*  kbt = (char*)d_ws + 65536;
        char*  vbt = kbt + kbt_bytes;

        hipMemsetAsync(d_ws, 0, 65536, stream);
        convkv<<<dim3(NBH * NTILE), dim3(256), 0, stream>>>(k, v, el, mv, kbt, vbt);
        flash14<<<dim3(NBH * 16), dim3(128), 0, stream>>>(q, el, mv, out, kbt, vbt, tk);
    } else {
        // fallback: proven R5 path
        float* mv = (float*)d_ws;
        int*   tk = (int*)((char*)d_ws + NBH * DH * sizeof(float));

        hipMemsetAsync(d_ws, 0, NBH * DH * sizeof(float) + 64, stream);
        meanv_k<<<dim3(NBH * 16), dim3(256), 0, stream>>>(v, mv);
        flash5<<<dim3(NBH * (SQ / 128)), dim3(256), 0, stream>>>(q, k, v, el, mv, out, tk);
    }
}

// Round 11
// 186.114 us; speedup vs baseline: 1.1973x; 1.0220x over previous
//
#include <hip/hip_runtime.h>
#include <hip/hip_bf16.h>

// InnocentAttention: B=4 H=16 S=2048 D=64, fp32 in/out, per-batch event_length mask.
//
// R16 = R15 resubmitted verbatim (R15's bench was an infra failure -- container
// died twice before running; no perf signal was obtained).
// R15: amortize the per-phase fixed cost. R6-R14 invariants: wall = one large
// item's serial chain of 64-key phases at ~5.5k cyc each, while issue-work is
// ~1.3k -- the rest is phase-fixed (barriers+waitcnt+latency walk), untouched
// by occupancy (15-37%), prefetch depth, drain semantics, or decorrelation.
// Fix: TK=128 phases -- one barrier-pair + one counted vmcnt per TWO 64-key
// subtiles; 16 phases instead of 32 for el=2048. LDS = 2-ring x 32KB = 64KB
// exactly; items statically assigned (it = blockIdx>>3; nvalid/group <= 64 =
// blocks/group) -- no ticket atomic, no item_s. All validated machinery kept:
// fragment-ordered workspace, XCD-affinity (head%8 == blockIdx%8), raw
// s_barrier (no vmcnt drain), counted VMCNT, setprio around MFMA.
// Falls back to the proven R5 path when ws_size < ~33.6 MB.

#define SQ 2048
#define DH 64
#define NBH 64
#define TK 64
#define NTILE 32           // SQ / TK
#define TILE_B 8192        // TK * DH * 2 bytes (bf16)
#define PH_B 16384         // 128-key phase = 2 ws tiles
#define LDE 72             // fallback-path padded LDS stride
#define LVP 68             // prepass V-stage stride

typedef __attribute__((ext_vector_type(4))) float f32x4;
typedef __attribute__((ext_vector_type(8))) short bf16x8;
typedef __attribute__((ext_vector_type(4))) unsigned int u32x4;
typedef __attribute__((ext_vector_type(2))) unsigned int u32x2;

#define VMCNT(n) asm volatile("s_waitcnt vmcnt(" #n ")" ::: "memory")
#define RAW_BARRIER() asm volatile("s_barrier" ::: "memory")

__device__ __forceinline__ unsigned int pk2(float lo, float hi) {
    // v_cvt_pk_bf16_f32 on gfx950 (RNE), lo -> low 16 bits
    __hip_bfloat162 h = __float22bfloat162_rn(float2{lo, hi});
    union { __hip_bfloat162 h; unsigned int u; } c; c.h = h;
    return c.u;
}

__device__ __forceinline__ float bfu16_to_f(unsigned short s) {
    union { unsigned int u; float f; } c; c.u = ((unsigned int)s) << 16;
    return c.f;
}

__device__ __forceinline__ void async_cp16(const void* g, void* l) {
    // global -> LDS direct DMA, 16B/lane; LDS dest = wave-uniform base + lane*16
    __builtin_amdgcn_global_load_lds(
        (const __attribute__((address_space(1))) unsigned int*)g,
        (__attribute__((address_space(3))) unsigned int*)l, 16, 0, 0);
}

// ============================================================================
// NEW PATH
// ============================================================================

// Prepass (validated R8-R14): one block per (bh, 64-key tile). Fragment-ordered:
//  K tile: line fi = mt*2+half (1KB); lane l=(qd*16+c): 16B =
//          K[key=mt*16+c][d = half*32+qd*8 .. +7] bf16.
//  V tile: line fi = kc*4+dt; lane l: element j =
//          V[key = kc*32 + (j>>2)*16 + qd*4 + (j&3)][d = dt*16+c]  (pi order)
//  MV[bh][d] += mean contribution of this tile's 64 V rows (atomic)
__global__ __launch_bounds__(256)
void convkv(const float* __restrict__ K, const float* __restrict__ V,
            const int* __restrict__ EL, float* __restrict__ MV,
            char* __restrict__ Kbt, char* __restrict__ Vbt) {
    const int bh = blockIdx.x >> 5;
    const int kt = blockIdx.x & 31;
    const int k0 = kt * TK;
    const int el = EL[bh >> 4];
    const int t = threadIdx.x;
    const int r  = t >> 2;      // key row 0..63
    const int dc = t & 3;       // 16-d chunk

    __shared__ short LV[64][LVP];

    // stage V row (bf16) into LDS for transpose + mean
    {
        const float* vp = V + ((size_t)bh * SQ + k0 + r) * DH + dc * 16;
        f32x4 a = *(const f32x4*)vp;
        f32x4 b = *(const f32x4*)(vp + 4);
        f32x4 c2 = *(const f32x4*)(vp + 8);
        f32x4 d2 = *(const f32x4*)(vp + 12);
        u32x4 w0, w1;
        w0[0] = pk2(a[0], a[1]);  w0[1] = pk2(a[2], a[3]);
        w0[2] = pk2(b[0], b[1]);  w0[3] = pk2(b[2], b[3]);
        w1[0] = pk2(c2[0], c2[1]); w1[1] = pk2(c2[2], c2[3]);
        w1[2] = pk2(d2[0], d2[1]); w1[3] = pk2(d2[2], d2[3]);
        *(u32x4*)&LV[r][dc * 16]     = w0;
        *(u32x4*)&LV[r][dc * 16 + 8] = w1;
    }

    // K convert (valid tiles only) -> fragment-ordered lines
    if (k0 < el) {
        const float* kp = K + ((size_t)bh * SQ + k0 + r) * DH + dc * 16;
        f32x4 a = *(const f32x4*)kp;
        f32x4 b = *(const f32x4*)(kp + 4);
        f32x4 c2 = *(const f32x4*)(kp + 8);
        f32x4 d2 = *(const f32x4*)(kp + 12);
        u32x4 w0, w1;
        w0[0] = pk2(a[0], a[1]);  w0[1] = pk2(a[2], a[3]);
        w0[2] = pk2(b[0], b[1]);  w0[3] = pk2(b[2], b[3]);
        w1[0] = pk2(c2[0], c2[1]); w1[1] = pk2(c2[2], c2[3]);
        w1[2] = pk2(d2[0], d2[1]); w1[3] = pk2(d2[2], d2[3]);
        char* kb = Kbt + (size_t)(bh * NTILE + kt) * TILE_B;
        const int fi  = (r >> 4) * 2 + (dc >> 1);
        const int qd0 = (dc & 1) * 2;
        char* d0 = kb + fi * 1024 + qd0 * 256 + (r & 15) * 16;
        *(u32x4*)d0         = w0;
        *(u32x4*)(d0 + 256) = w1;
    }

    __syncthreads();

    // transpose-read V in pi order + mean partial
    const int dd  = t >> 2;     // d row 0..63
    const int seg = t & 3;      // 16-pos segment
    float msum = 0.f;
    unsigned int wv[8];
    #pragma unroll
    for (int i = 0; i < 8; ++i) {
        const int pos = seg * 16 + 2 * i;
        const int key = (pos & ~31) | ((pos & 4) << 2) | ((pos & 24) >> 1) | (pos & 3);
        const unsigned short s0 = (unsigned short)LV[key][dd];
        const unsigned short s1 = (unsigned short)LV[key + 1][dd];
        msum += bfu16_to_f(s0) + bfu16_to_f(s1);
        wv[i] = (unsigned int)s0 | ((unsigned int)s1 << 16);
    }
    msum += __shfl_xor(msum, 1);
    msum += __shfl_xor(msum, 2);
    if (seg == 0) atomicAdd(&MV[bh * DH + dd], msum * (1.0f / (float)SQ));

    if (k0 < el) {
        char* vbb = Vbt + (size_t)(bh * NTILE + kt) * TILE_B;
        const int fi  = (seg >> 1) * 4 + (dd >> 4);
        const int qd0 = (seg & 1) * 2;
        char* d0 = vbb + fi * 1024 + qd0 * 256 + (dd & 15) * 16;
        u32x4 o0 = {wv[0], wv[1], wv[2], wv[3]};
        u32x4 o1 = {wv[4], wv[5], wv[6], wv[7]};
        *(u32x4*)d0         = o0;
        *(u32x4*)(d0 + 256) = o1;
    }
}

// Main kernel: 512 threads = 8 waves x 32 queries = one STATIC 256-q item per
// block. 128-key phases (2 subtiles), 2-slot 64KB ring, raw barriers, counted
// vmcnt, per-XCD affinity.
__global__ __launch_bounds__(512, 4)
void flash15(const float* __restrict__ Q, const int* __restrict__ EL,
             const float* __restrict__ MV, float* __restrict__ O,
             const char* __restrict__ Kbt, const char* __restrict__ Vbt) {
    const int t = threadIdx.x;

    // ---------- static phase: mean(V) rows for own fully-masked q-block ------
    {
        const int bh0 = blockIdx.x & (NBH - 1);
        const int qb0 = (blockIdx.x >> 6) * 256;     // grid 512: 8 chunks of 256q
        const int elb = EL[bh0 >> 4];
        if (qb0 >= elb) {
            float* Op = O + (size_t)bh0 * SQ * DH;
            const int c16 = t & 15, r0 = t >> 4;     // r0 0..31
            f32x4 mv = *(const f32x4*)(MV + bh0 * DH + c16 * 4);
            #pragma unroll
            for (int i = 0; i < 8; ++i)
                *(f32x4*)(Op + (size_t)(qb0 + r0 + i * 32) * DH + c16 * 4) = mv;
        }
    }

    // ---------- batch table, sorted descending by el (register network) ------
    int ka0 = EL[0], va0 = 0;
    int ka1 = EL[1], va1 = 1;
    int ka2 = EL[2], va2 = 2;
    int ka3 = EL[3], va3 = 3;
    #define CSWAP(x, y) if (ka##x < ka##y) { int tk_ = ka##x, tv_ = va##x; \
        ka##x = ka##y; va##x = va##y; ka##y = tk_; va##y = tv_; }
    CSWAP(0, 1) CSWAP(2, 3) CSWAP(0, 2) CSWAP(1, 3) CSWAP(1, 2)
    #undef CSWAP
    const int c0 = 2 * ((ka0 + 255) >> 8);   // items per (group, batch): 2 heads x qtiles
    const int c1 = 2 * ((ka1 + 255) >> 8);
    const int c2 = 2 * ((ka2 + 255) >> 8);
    const int c3 = 2 * ((ka3 + 255) >> 8);
    const int nvalid = c0 + c1 + c2 + c3;    // <= 64 == blocks per group

    __shared__ char KB[2 * PH_B];            // 2-slot ring, 128-key K phases
    __shared__ char VB[2 * PH_B];            // 2-slot ring, 128-key V phases

    const int grp = blockIdx.x & 7;          // blockIdx%8 ~ XCD (perf-only)
    const int it  = blockIdx.x >> 3;         // static item id within group
    if (it >= nvalid) return;

    // decode (largest batch first)
    int u = it, b, el;
    if (u < c0)             { b = va0; el = ka0; }
    else { u -= c0;
    if (u < c1)             { b = va1; el = ka1; }
    else { u -= c1;
    if (u < c2)             { b = va2; el = ka2; }
    else { u -= c2;           b = va3; el = ka3; } } }
    const int vb_ = (el + 255) >> 8;
    const int hh  = u / vb_;
    const int qt  = u - hh * vb_;
    const int bh  = b * 16 + grp + hh * 8;   // head%8 == grp -> L2 affinity
    const int qbase = qt * 256;

    const int wq = t >> 6, lane = t & 63, qd = lane >> 4, c = lane & 15;
    const float sc = 0.125f * 1.44269504f;   // 1/sqrt(D) * log2(e)

    const float* Qp = Q + (size_t)bh * SQ * DH;
    float*       Op = O + (size_t)bh * SQ * DH;
    const char*  Kt = Kbt + (size_t)bh * NTILE * TILE_B + t * 16;
    const char*  Vt = Vbt + (size_t)bh * NTILE * TILE_B + t * 16;

    const int nph = (el + 127) >> 7;         // 128-key phases

    // per-thread staging: 512 thr x 16B x 2 rounds = 16KB (one phase of K or V)
    #define STAGE(ph_, s_) {                                                   \
        const char* gk_ = Kt + (size_t)(ph_) * PH_B;                           \
        const char* gv_ = Vt + (size_t)(ph_) * PH_B;                           \
        char* lk_ = KB + (s_) * PH_B + t * 16;                                 \
        char* lv_ = VB + (s_) * PH_B + t * 16;                                 \
        async_cp16(gk_,        lk_);                                           \
        async_cp16(gk_ + 8192, lk_ + 8192);                                    \
        async_cp16(gv_,        lv_);                                           \
        async_cp16(gv_ + 8192, lv_ + 8192);                                    \
    }

    // prologue: phase 0 in flight (4 VMEM instr/thread)
    STAGE(0, 0)

    // Q fragments (B-operand of S^T = K*Q^T); scale folded in
    bf16x8 qf[2][2];
    #pragma unroll
    for (int nt = 0; nt < 2; ++nt) {
        const int row = qbase + wq * 32 + nt * 16 + c;
        #pragma unroll
        for (int kc = 0; kc < 2; ++kc) {
            const float* p = Qp + (size_t)row * DH + kc * 32 + qd * 8;
            f32x4 a  = *(const f32x4*)p;
            f32x4 bq = *(const f32x4*)(p + 4);
            u32x4 f;
            f[0] = pk2(a[0] * sc, a[1] * sc);
            f[1] = pk2(a[2] * sc, a[3] * sc);
            f[2] = pk2(bq[0] * sc, bq[1] * sc);
            f[3] = pk2(bq[2] * sc, bq[3] * sc);
            qf[nt][kc] = *(bf16x8*)&f;
        }
    }

    float l_[2] = {0.f, 0.f};
    f32x4 oacc[4][2];
    #pragma unroll
    for (int dt = 0; dt < 4; ++dt) {
        oacc[dt][0] = (f32x4){0.f, 0.f, 0.f, 0.f};
        oacc[dt][1] = (f32x4){0.f, 0.f, 0.f, 0.f};
    }

    for (int ph = 0; ph < nph; ++ph) {
        const int s = ph & 1;

        // all waves finished phase ph-1 -> slot s^1 reusable.
        RAW_BARRIER();
        if (ph + 1 < nph) STAGE(ph + 1, s ^ 1)
        // counted wait: own phase-ph copies done; next phase stays in flight
        if (ph + 1 < nph) VMCNT(4); else VMCNT(0);
        RAW_BARRIER();                       // everyone's phase-ph lines visible

        // ---- two 64-key subtiles per phase ----
        #pragma unroll
        for (int su = 0; su < 2; ++su) {
            const int k0 = ph * 128 + su * 64;
            if (k0 >= el) break;             // garbage subtile: skip entirely

            const char* Kb = KB + s * PH_B + su * TILE_B + lane * 16;
            const char* Vb = VB + s * PH_B + su * TILE_B + lane * 16;

            // ---- S^T = K * Q^T : contiguous fragment-line reads ----
            f32x4 st[4][2];
            __builtin_amdgcn_s_setprio(1);
            #pragma unroll
            for (int mt = 0; mt < 4; ++mt) {
                bf16x8 a0 = *(const bf16x8*)(Kb + (mt * 2) * 1024);
                bf16x8 a1 = *(const bf16x8*)(Kb + (mt * 2 + 1) * 1024);
                #pragma unroll
                for (int nt = 0; nt < 2; ++nt) {
                    f32x4 acc = (f32x4){0.f, 0.f, 0.f, 0.f};
                    acc = __builtin_amdgcn_mfma_f32_16x16x32_bf16(a0, qf[nt][0], acc, 0, 0, 0);
                    acc = __builtin_amdgcn_mfma_f32_16x16x32_bf16(a1, qf[nt][1], acc, 0, 0, 0);
                    st[mt][nt] = acc;
                }
            }
            __builtin_amdgcn_s_setprio(0);

            if (k0 + TK > el) {    // straddling subtile: mask invalid keys
                #pragma unroll
                for (int mt = 0; mt < 4; ++mt)
                    #pragma unroll
                    for (int r = 0; r < 4; ++r)
                        if (k0 + mt * 16 + qd * 4 + r >= el) {
                            st[mt][0][r] = -1e30f;
                            st[mt][1][r] = -1e30f;
                        }
            }

            // ---- p = exp2(s); pack in-register (pi order == lane's own keys) ----
            u32x4 pw[2][2];
            #pragma unroll
            for (int nt = 0; nt < 2; ++nt) {
                #pragma unroll
                for (int mt = 0; mt < 4; ++mt) {
                    const float p0 = __builtin_amdgcn_exp2f(st[mt][nt][0]);
                    const float p1 = __builtin_amdgcn_exp2f(st[mt][nt][1]);
                    const float p2 = __builtin_amdgcn_exp2f(st[mt][nt][2]);
                    const float p3 = __builtin_amdgcn_exp2f(st[mt][nt][3]);
                    l_[nt] += (p0 + p1) + (p2 + p3);
                    pw[nt][mt >> 1][(mt & 1) * 2]     = pk2(p0, p1);
                    pw[nt][mt >> 1][(mt & 1) * 2 + 1] = pk2(p2, p3);
                }
            }

            // ---- O^T += V^T * P^T : V lines pi-permuted, P in-register ----
            __builtin_amdgcn_s_setprio(1);
            #pragma unroll
            for (int kc = 0; kc < 2; ++kc) {
                bf16x8 pb0 = *(bf16x8*)&pw[0][kc];
                bf16x8 pb1 = *(bf16x8*)&pw[1][kc];
                #pragma unroll
                for (int dt = 0; dt < 4; ++dt) {
                    bf16x8 vf = *(const bf16x8*)(Vb + (kc * 4 + dt) * 1024);
                    oacc[dt][0] = __builtin_amdgcn_mfma_f32_16x16x32_bf16(vf, pb0, oacc[dt][0], 0, 0, 0);
                    oacc[dt][1] = __builtin_amdgcn_mfma_f32_16x16x32_bf16(vf, pb1, oacc[dt][1], 0, 0, 0);
                }
            }
            __builtin_amdgcn_s_setprio(0);
        }
    }
    #undef STAGE

    // denominators: cross-lane combine over qd groups (same query col c)
    #pragma unroll
    for (int nt = 0; nt < 2; ++nt) {
        l_[nt] += __shfl_xor(l_[nt], 16);
        l_[nt] += __shfl_xor(l_[nt], 32);
    }

    #pragma unroll
    for (int nt = 0; nt < 2; ++nt) {
        const int qrow = qbase + wq * 32 + nt * 16 + c;
        if (qrow < el) {
            const float inv = 1.0f / l_[nt];
            #pragma unroll
            for (int dt = 0; dt < 4; ++dt) {
                f32x4 o = oacc[dt][nt];
                o[0] *= inv; o[1] *= inv; o[2] *= inv; o[3] *= inv;
                *(f32x4*)(Op + (size_t)qrow * DH + dt * 16 + qd * 4) = o;
            }
        } else {
            #pragma unroll
            for (int dt = 0; dt < 4; ++dt)
                *(f32x4*)(Op + (size_t)qrow * DH + dt * 16 + qd * 4) =
                    *(const f32x4*)(MV + bh * DH + dt * 16 + qd * 4);
        }
    }
}

// ============================================================================
// FALLBACK PATH (proven R5 kernels, used when ws_size < ~33.6 MB)
// ============================================================================

__global__ __launch_bounds__(256)
void meanv_k(const float* __restrict__ V, float* __restrict__ MV) {
    const int bh  = blockIdx.x >> 4;
    const int seg = blockIdx.x & 15;
    const float* vp = V + ((size_t)bh * SQ + (size_t)seg * 128) * DH;
    const int c = threadIdx.x & 15;
    const int r = threadIdx.x >> 4;
    const float* p = vp + (size_t)r * DH + c * 4;
    f32x4 s0 = *(const f32x4*)(p);
    f32x4 s1 = *(const f32x4*)(p + 16 * DH);
    f32x4 s2 = *(const f32x4*)(p + 32 * DH);
    f32x4 s3 = *(const f32x4*)(p + 48 * DH);
    s0 += *(const f32x4*)(p + 64 * DH);
    s1 += *(const f32x4*)(p + 80 * DH);
    s2 += *(const f32x4*)(p + 96 * DH);
    s3 += *(const f32x4*)(p + 112 * DH);
    f32x4 s = (s0 + s1) + (s2 + s3);
    __shared__ f32x4 red[16][16];
    red[r][c] = s;
    __syncthreads();
    if (threadIdx.x < 16) {
        f32x4 a = red[0][threadIdx.x];
        #pragma unroll
        for (int j = 1; j < 16; ++j) a += red[j][threadIdx.x];
        const float inv = 1.0f / (float)SQ;
        atomicAdd(&MV[bh * DH + threadIdx.x * 4 + 0], a[0] * inv);
        atomicAdd(&MV[bh * DH + threadIdx.x * 4 + 1], a[1] * inv);
        atomicAdd(&MV[bh * DH + threadIdx.x * 4 + 2], a[2] * inv);
        atomicAdd(&MV[bh * DH + threadIdx.x * 4 + 3], a[3] * inv);
    }
}

__global__ __launch_bounds__(256, 3)
void flash5(const float* __restrict__ Q, const float* __restrict__ K,
            const float* __restrict__ V, const int* __restrict__ EL,
            const float* __restrict__ MV, float* __restrict__ O,
            int* __restrict__ ticket) {
    const int t = threadIdx.x;
    {
        const int bh0    = blockIdx.x & (NBH - 1);
        const int qbase0 = (blockIdx.x >> 6) * 128;
        const int elb    = EL[bh0 >> 4];
        if (qbase0 >= elb) {
            float* Op = O + (size_t)bh0 * SQ * DH;
            const int c16 = t & 15, r0 = t >> 4;
            f32x4 mv = *(const f32x4*)(MV + bh0 * DH + c16 * 4);
            #pragma unroll
            for (int i = 0; i < 8; ++i)
                *(f32x4*)(Op + (size_t)(qbase0 + r0 + i * 16) * DH + c16 * 4) = mv;
        }
    }

    const int el0 = EL[0], el1 = EL[1], el2 = EL[2], el3 = EL[3];
    const int v0 = (el0 + 127) >> 7, v1 = (el1 + 127) >> 7;
    const int v2 = (el2 + 127) >> 7, v3 = (el3 + 127) >> 7;
    const int n0 = 16 * v0, n1 = n0 + 16 * v1, n2 = n1 + 16 * v2;
    const int nvalid = n2 + 16 * v3;

    __shared__ short Kb[TK][LDE];
    __shared__ short Vt[DH][LDE];
    __shared__ short Pl[4][32][LDE];
    __shared__ int item_s;

    const int wq = t >> 6, lane = t & 63, qd = lane >> 4, c = lane & 15;
    const int ksrow = t >> 2;
    const int ksdc  = t & 3;
    const int vpair = t & 31;
    const int vdg   = t >> 5;

    for (;;) {
        if (t == 0) item_s = atomicAdd(ticket, 1);
        __syncthreads();
        const int it = item_s;
        if (it >= nvalid) break;

        int b, u, vb, el;
        if      (it < n0) { b = 0; u = it;      vb = v0; el = el0; }
        else if (it < n1) { b = 1; u = it - n0; vb = v1; el = el1; }
        else if (it < n2) { b = 2; u = it - n1; vb = v2; el = el2; }
        else              { b = 3; u = it - n2; vb = v3; el = el3; }
        const int head  = u / vb;
        const int qt    = u - head * vb;
        const int bh    = b * 16 + head;
        const int qbase = qt * 128;

        const size_t base = (size_t)bh * SQ * DH;
        const float* Qp = Q + base;
        const float* Kp = K + base;
        const float* Vp = V + base;
        float* Op = O + base;

        const float sc = 0.125f * 1.44269504f;
        bf16x8 qf[2][2];
        #pragma unroll
        for (int nt = 0; nt < 2; ++nt) {
            const int row = qbase + wq * 32 + nt * 16 + c;
            #pragma unroll
            for (int kc = 0; kc < 2; ++kc) {
                const float* p = Qp + (size_t)row * DH + kc * 32 + qd * 8;
                f32x4 a  = *(const f32x4*)p;
                f32x4 bb = *(const f32x4*)(p + 4);
                u32x4 f;
                f[0] = pk2(a[0] * sc, a[1] * sc);
                f[1] = pk2(a[2] * sc, a[3] * sc);
                f[2] = pk2(bb[0] * sc, bb[1] * sc);
                f[3] = pk2(bb[2] * sc, bb[3] * sc);
                qf[nt][kc] = *(bf16x8*)&f;
            }
        }

        float l_[2] = {0.f, 0.f};
        f32x4 oacc[4][2];
        #pragma unroll
        for (int dt = 0; dt < 4; ++dt)
            #pragma unroll
            for (int nt = 0; nt < 2; ++nt)
                oacc[dt][nt] = (f32x4){0.f, 0.f, 0.f, 0.f};

        const int nkt = (el + TK - 1) / TK;

        f32x4 kg0, kg1, kg2, kg3, vg0, vg1, vg2, vg3;
        {
            const float* kp = Kp + (size_t)ksrow * DH + ksdc * 16;
            kg0 = *(const f32x4*)kp;
            kg1 = *(const f32x4*)(kp + 4);
            kg2 = *(const f32x4*)(kp + 8);
            kg3 = *(const f32x4*)(kp + 12);
            const float* vp0 = Vp + (size_t)(2 * vpair) * DH + vdg * 8;
            vg0 = *(const f32x4*)vp0;
            vg1 = *(const f32x4*)(vp0 + 4);
            vg2 = *(const f32x4*)(vp0 + DH);
            vg3 = *(const f32x4*)(vp0 + DH + 4);
        }

        for (int kt = 0; kt < nkt; ++kt) {
            const int k0 = kt * TK;

            __syncthreads();
            {
                u32x4 w0, w1;
                w0[0] = pk2(kg0[0], kg0[1]); w0[1] = pk2(kg0[2], kg0[3]);
                w0[2] = pk2(kg1[0], kg1[1]); w0[3] = pk2(kg1[2], kg1[3]);
                w1[0] = pk2(kg2[0], kg2[1]); w1[1] = pk2(kg2[2], kg2[3]);
                w1[2] = pk2(kg3[0], kg3[1]); w1[3] = pk2(kg3[2], kg3[3]);
                *(u32x4*)&Kb[ksrow][ksdc * 16]     = w0;
                *(u32x4*)&Kb[ksrow][ksdc * 16 + 8] = w1;
            }
            {
                #pragma unroll
                for (int i = 0; i < 4; ++i) {
                    *(unsigned int*)&Vt[vdg * 8 + i][2 * vpair]     = pk2(vg0[i], vg2[i]);
                    *(unsigned int*)&Vt[vdg * 8 + 4 + i][2 * vpair] = pk2(vg1[i], vg3[i]);
                }
            }
            __syncthreads();

            if (kt + 1 < nkt) {
                const int kn = k0 + TK;
                const float* kp = Kp + (size_t)(kn + ksrow) * DH + ksdc * 16;
                kg0 = *(const f32x4*)kp;
                kg1 = *(const f32x4*)(kp + 4);
                kg2 = *(const f32x4*)(kp + 8);
                kg3 = *(const f32x4*)(kp + 12);
                const float* vp0 = Vp + (size_t)(kn + 2 * vpair) * DH + vdg * 8;
                vg0 = *(const f32x4*)vp0;
                vg1 = *(const f32x4*)(vp0 + 4);
                vg2 = *(const f32x4*)(vp0 + DH);
                vg3 = *(const f32x4*)(vp0 + DH + 4);
            }

            f32x4 st[4][2];
            #pragma unroll
            for (int mt = 0; mt < 4; ++mt) {
                bf16x8 a0 = *(const bf16x8*)&Kb[mt * 16 + c][qd * 8];
                bf16x8 a1 = *(const bf16x8*)&Kb[mt * 16 + c][32 + qd * 8];
                #pragma unroll
                for (int nt = 0; nt < 2; ++nt) {
                    f32x4 acc = (f32x4){0.f, 0.f, 0.f, 0.f};
                    acc = __builtin_amdgcn_mfma_f32_16x16x32_bf16(a0, qf[nt][0], acc, 0, 0, 0);
                    acc = __builtin_amdgcn_mfma_f32_16x16x32_bf16(a1, qf[nt][1], acc, 0, 0, 0);
                    st[mt][nt] = acc;
                }
            }

            if (k0 + TK > el) {
                #pragma unroll
                for (int mt = 0; mt < 4; ++mt)
                    #pragma unroll
                    for (int r = 0; r < 4; ++r)
                        if (k0 + mt * 16 + qd * 4 + r >= el) {
                            st[mt][0][r] = -1e30f;
                            st[mt][1][r] = -1e30f;
                        }
            }

            #pragma unroll
            for (int nt = 0; nt < 2; ++nt) {
                #pragma unroll
                for (int mt = 0; mt < 4; ++mt) {
                    const float p0 = exp2f(st[mt][nt][0]);
                    const float p1 = exp2f(st[mt][nt][1]);
                    const float p2 = exp2f(st[mt][nt][2]);
                    const float p3 = exp2f(st[mt][nt][3]);
                    l_[nt] += (p0 + p1) + (p2 + p3);
                    u32x2 pw;
                    pw[0] = pk2(p0, p1);
                    pw[1] = pk2(p2, p3);
                    *(u32x2*)&Pl[wq][nt * 16 + c][mt * 16 + qd * 4] = pw;
                }
            }

            #pragma unroll
            for (int kc = 0; kc < 2; ++kc) {
                bf16x8 pb0 = *(const bf16x8*)&Pl[wq][c][kc * 32 + qd * 8];
                bf16x8 pb1 = *(const bf16x8*)&Pl[wq][16 + c][kc * 32 + qd * 8];
                #pragma unroll
                for (int dt = 0; dt < 4; ++dt) {
                    bf16x8 vf = *(const bf16x8*)&Vt[dt * 16 + c][kc * 32 + qd * 8];
                    oacc[dt][0] = __builtin_amdgcn_mfma_f32_16x16x32_bf16(vf, pb0, oacc[dt][0], 0, 0, 0);
                    oacc[dt][1] = __builtin_amdgcn_mfma_f32_16x16x32_bf16(vf, pb1, oacc[dt][1], 0, 0, 0);
                }
            }
        }

        #pragma unroll
        for (int nt = 0; nt < 2; ++nt) {
            l_[nt] += __shfl_xor(l_[nt], 16);
            l_[nt] += __shfl_xor(l_[nt], 32);
        }

        #pragma unroll
        for (int nt = 0; nt < 2; ++nt) {
            const int row = qbase + wq * 32 + nt * 16 + c;
            if (row < el) {
                const float inv = 1.0f / l_[nt];
                #pragma unroll
                for (int dt = 0; dt < 4; ++dt) {
                    f32x4 o = oacc[dt][nt];
                    o[0] *= inv; o[1] *= inv; o[2] *= inv; o[3] *= inv;
                    *(f32x4*)(Op + (size_t)row * DH + dt * 16 + qd * 4) = o;
                }
            } else {
                #pragma unroll
                for (int dt = 0; dt < 4; ++dt) {
                    f32x4 mv = *(const f32x4*)(MV + bh * DH + dt * 16 + qd * 4);
                    *(f32x4*)(Op + (size_t)row * DH + dt * 16 + qd * 4) = mv;
                }
            }
        }
    }
}

// ============================================================================

extern "C" void kernel_launch(void* const* d_in, const int* in_sizes, int n_in,
                              void* d_out, int out_size, void* d_ws, size_t ws_size,
                              hipStream_t stream) {
    const float* q  = (const float*)d_in[0];
    const float* k  = (const float*)d_in[1];
    const float* v  = (const float*)d_in[2];
    const int*   el = (const int*)d_in[3];
    float* out = (float*)d_out;

    const size_t kbt_bytes = (size_t)NBH * NTILE * TILE_B;      // 16 MiB
    const size_t needed    = 65536 + 2 * kbt_bytes;             // ~33.6 MiB

    if (ws_size >= needed) {
        // new path: fragment-ordered prepass + 128-key-phase static flash
        float* mv  = (float*)d_ws;
        char*  kbt = (char*)d_ws + 65536;
        char*  vbt = kbt + kbt_bytes;

        hipMemsetAsync(d_ws, 0, 65536, stream);
        convkv<<<dim3(NBH * NTILE), dim3(256), 0, stream>>>(k, v, el, mv, kbt, vbt);
        flash15<<<dim3(NBH * (SQ / 256)), dim3(512), 0, stream>>>(q, el, mv, out, kbt, vbt);
    } else {
        // fallback: proven R5 path
        float* mv = (float*)d_ws;
        int*   tk = (int*)((char*)d_ws + NBH * DH * sizeof(float));

        hipMemsetAsync(d_ws, 0, NBH * DH * sizeof(float) + 64, stream);
        meanv_k<<<dim3(NBH * 16), dim3(256), 0, stream>>>(v, mv);
        flash5<<<dim3(NBH * (SQ / 128)), dim3(256), 0, stream>>>(q, k, v, el, mv, out, tk);
    }
}